// Round 4
// baseline (346.333 us; speedup 1.0000x reference)
//
#include <hip/hip_runtime.h>
#include <stdint.h>

#define T_LEN 4096
#define PAD   128
#define HROWS (T_LEN + 2*PAD)   // 4352 rows (zero pad 128 each side)
#define NCH   256
#define M2    512
#define BG    4
#define NL    8

using f4  = __attribute__((ext_vector_type(4))) float;
using bh8 = __attribute__((ext_vector_type(8))) short;
using s4v = __attribute__((ext_vector_type(4))) short;
using u4  = __attribute__((ext_vector_type(4))) unsigned int;

static __device__ __forceinline__ short f2b(float f){
  unsigned u = __builtin_bit_cast(unsigned, f);
  unsigned r = (u + 0x7FFFu + ((u >> 16) & 1u)) >> 16;
  return (short)r;
}
static __device__ __forceinline__ float b2f(short s){
  unsigned u = ((unsigned)(unsigned short)s) << 16;
  return __builtin_bit_cast(float, u);
}

#define MFMA(a,b,c) __builtin_amdgcn_mfma_f32_16x16x32_bf16((a),(b),(c),0,0,0)

// ---------------- prep: weights -> bf16, fragment-ordered relayout ----------------
// W1s[l][tap][og(8)][kk(8)][mf(4)][lane(64)][8]: o = og*64+mf*16+(lane&15), c = kk*32+(lane>>4)*8+j
// W2s[l][og(4)][kk][mf][lane][8]: res half only (o<256); l==7 -> 0 (unused)
// rsb8[l][o]: l<7 -> rs_b[l][o]; l==7 unused (0)
// Wc[o][k] (k padded 80->128) = cond_w[o][k]
__global__ void prep_w(const float* __restrict__ in_w, const float* __restrict__ rs_w,
                       const float* __restrict__ rs_b, const float* __restrict__ cond_w,
                       short* __restrict__ W1, short* __restrict__ W2, float* __restrict__ rsb8,
                       short* __restrict__ Wc){
  const int n1 = NL*3*M2*NCH;           // 3,145,728
  const int n2 = NL*4*8*4*64*8;         // 524,288
  const int n3 = NL*M2;                 // 4,096
  const int n4 = 4096*128;              // 524,288
  for (int i = blockIdx.x*blockDim.x + threadIdx.x; i < n1+n2+n3+n4; i += gridDim.x*blockDim.x){
    if (i < n1){
      int j = i & 7, lane = (i >> 3) & 63, mf = (i >> 9) & 3, kk = (i >> 11) & 7, og = (i >> 14) & 7;
      int lt = i >> 17;                 // l*3 + tap
      int tap = lt % 3, l = lt / 3;
      int o = og*64 + mf*16 + (lane & 15);
      int c = kk*32 + (lane >> 4)*8 + j;
      W1[i] = f2b(in_w[(((l*M2 + o)*NCH + c)*3) + tap]);
    } else if (i < n1+n2){
      int q = i - n1;
      int j = q & 7, lane = (q >> 3) & 63, mf = (q >> 9) & 3, kk = (q >> 11) & 7, og = (q >> 14) & 3;
      int l = q >> 16;
      int o = og*64 + mf*16 + (lane & 15);    // 0..255 (res half)
      int c = kk*32 + (lane >> 4)*8 + j;
      W2[q] = (l < 7) ? f2b(rs_w[((size_t)(l*M2 + o))*NCH + c]) : (short)0;
    } else if (i < n1+n2+n3){
      int k = i - n1 - n2;
      int o = k & 511, l = k >> 9;
      rsb8[k] = (l < 7) ? rs_b[l*M2 + o] : 0.f;
    } else {
      int j = i - n1 - n2 - n3;
      int k = j & 127, o = j >> 7;
      Wc[j] = (k < 80) ? f2b(cond_w[o*80 + k]) : (short)0;
    }
  }
}

// ---------------- prep: zero only the pad rows of hA/hB ----------------
__global__ void prep_pad(short* __restrict__ hA, short* __restrict__ hB){
  int i = blockIdx.x*blockDim.x + threadIdx.x;     // 0..65535 (u4 writes)
  short* h = (i < 32768) ? hA : hB;
  int j = (i & 32767) << 3;                        // short index in pad region
  int b = j >> 16;                                 // 2*PAD*NCH = 65536 shorts per batch
  int r = j & 65535;
  int row = r >> 8;                                // 0..255
  int c = r & 255;
  int grow = (row < PAD) ? row : (T_LEN + PAD + (row - PAD));
  *(u4*)(h + ((size_t)b*HROWS + grow)*NCH + c) = (u4){0,0,0,0};
}

// ---------------- prep: E_l = end_w @ W2hi_l (16x256, fragment-ordered bf16) + ebl ----------------
__global__ void prep_E(const float* __restrict__ rs_w, const float* __restrict__ rs_last_w,
                       const float* __restrict__ rs_b, const float* __restrict__ rs_last_b,
                       const float* __restrict__ end_w, const float* __restrict__ end_b,
                       short* __restrict__ Es, float* __restrict__ ebl){
  __shared__ float ew[16*256];
  int l = blockIdx.x;
  int c = threadIdx.x;   // 0..255
  for (int i = threadIdx.x; i < 16*256; i += 256) ew[i] = end_w[i];
  __syncthreads();
  float acc[16];
  #pragma unroll
  for (int o = 0; o < 16; ++o) acc[o] = 0.f;
  for (int cp = 0; cp < 256; ++cp){
    float wv = (l < 7) ? rs_w[((size_t)(l*M2 + NCH + cp))*NCH + c]
                       : rs_last_w[(size_t)cp*NCH + c];
    #pragma unroll
    for (int o = 0; o < 16; ++o) acc[o] += ew[o*256 + cp] * wv;
  }
  // Es[l][kk(8)][lane(64)][8]: o=lane&15, c=kk*32+(lane>>4)*8+j
  int kk = c >> 5, g = (c >> 3) & 3, j = c & 7;
  #pragma unroll
  for (int o = 0; o < 16; ++o)
    Es[(((size_t)l*8 + kk)*64 + g*16 + o)*8 + j] = f2b(acc[o]);
  if (c < 16){
    float s = (l == 0) ? end_b[c] : 0.f;
    for (int cp = 0; cp < 256; ++cp){
      float bv = (l < 7) ? rs_b[l*M2 + NCH + cp] : rs_last_b[cp];
      s += ew[c*256 + cp] * bv;
    }
    ebl[l*16 + c] = s;
  }
}

// ---------------- prep: spectT[t][128 k] bf16 (padded transpose) ----------------
__global__ void prep_spectT(const float* __restrict__ spect, short* __restrict__ spectT){
  __shared__ float tile[64][65];
  int t0 = blockIdx.x*64, k0 = blockIdx.y*64;
  for (int i = threadIdx.x; i < 64*64; i += 256){
    int kr = i >> 6, tt = i & 63;
    int k = k0 + kr;
    tile[kr][tt] = (k < 80) ? spect[(size_t)k*T_LEN + t0 + tt] : 0.f;
  }
  __syncthreads();
  for (int i = threadIdx.x; i < 64*64; i += 256){
    int r = i >> 6, kk = i & 63;
    spectT[(size_t)(t0 + r)*128 + k0 + kk] = f2b(tile[kk][r]);
  }
}

// ---------------- prep: cb[b][ch] = in_b[ch] + pos_lin_b[ch] + pc[b][ch] ----------------
__global__ void prep_cb(const int* __restrict__ pos, const float* __restrict__ pos_emb_w,
                        const float* __restrict__ pos_lin_w, const float* __restrict__ pos_lin_b,
                        const float* __restrict__ in_b, float* __restrict__ cb){
  int b = blockIdx.y;
  int ch = blockIdx.x*blockDim.x + threadIdx.x;     // 0..4095
  int p = pos[b];
  float acc = pos_lin_b[ch] + in_b[ch];
  for (int k = 0; k < 128; ++k){
    float e = pos_emb_w[p*128 + k];
    e = e > 0.f ? e : 0.f;
    acc += e * pos_lin_w[ch*128 + k];
  }
  cb[b*4096 + ch] = acc;
}

// ---------------- prep: h0[b][t][c] (bf16, padded layout) ----------------
__global__ void prep_h0(const float* __restrict__ audio, const float* __restrict__ start_w,
                        const float* __restrict__ start_b, short* __restrict__ hA){
  __shared__ float sw[NCH*8];
  __shared__ float sb[NCH];
  int b = blockIdx.y, t0 = blockIdx.x*64;
  for (int i = threadIdx.x; i < NCH*8; i += 256) sw[i] = start_w[i];
  for (int i = threadIdx.x; i < NCH;   i += 256) sb[i] = start_b[i];
  __syncthreads();
  int t = t0 + (threadIdx.x & 63);
  int cg = threadIdx.x >> 6;
  float av[8];
  #pragma unroll
  for (int ic = 0; ic < 8; ++ic) av[ic] = audio[((size_t)(b*8 + ic))*T_LEN + t];
  short* dst = hA + ((size_t)b*HROWS + PAD + t)*NCH;
  for (int c = cg*64; c < cg*64 + 64; ++c){
    float acc = sb[c];
    #pragma unroll
    for (int ic = 0; ic < 8; ++ic) acc += sw[c*8 + ic]*av[ic];
    dst[c] = f2b(acc);
  }
}

// ---------------- cond GEMM: fragment-ordered output ----------------
// condF[l][tile(64)][w(8)][mfnf(16)][lane(64)][4]; grid (64 t-tiles, 8 layers)
__global__ __launch_bounds__(512, 2) void cond_gemm(
    const short* __restrict__ Wc, const short* __restrict__ spectT,
    const float* __restrict__ cond_b, short* __restrict__ cond){
  __shared__ short St[64*128];   // 16 KB, [t][k] XOR-swizzled
  const int tid = threadIdx.x;
  const int w = tid >> 6, lane = tid & 63;
  const int l15 = lane & 15, g = lane >> 4;
  const int t0 = blockIdx.x*64, ch0 = blockIdx.y*512;
  const int orow = w << 6;

  #pragma unroll
  for (int s = 0; s < 2; ++s){
    int id = tid + s*512;
    int r = id >> 4, c8 = (id & 15) << 3;
    u4 v = *(const u4*)(spectT + (size_t)(t0 + r)*128 + c8);
    *(u4*)(St + r*128 + (c8 ^ ((r & 7) << 3))) = v;
  }
  __syncthreads();

  f4 acc[4][4];
  #pragma unroll
  for (int mf = 0; mf < 4; ++mf)
    #pragma unroll
    for (int nf = 0; nf < 4; ++nf) acc[mf][nf] = (f4){0.f,0.f,0.f,0.f};

  #pragma unroll
  for (int kk = 0; kk < 3; ++kk){
    bh8 av[4], bv[4];
    #pragma unroll
    for (int mf = 0; mf < 4; ++mf)
      av[mf] = *(const bh8*)(Wc + (size_t)(ch0 + orow + mf*16 + l15)*128 + kk*32 + g*8);
    #pragma unroll
    for (int nf = 0; nf < 4; ++nf){
      int t = nf*16 + l15;
      bv[nf] = *(const bh8*)(St + t*128 + ((kk*32 + g*8) ^ ((t & 7) << 3)));
    }
    #pragma unroll
    for (int mf = 0; mf < 4; ++mf)
      #pragma unroll
      for (int nf = 0; nf < 4; ++nf)
        acc[mf][nf] = MFMA(av[mf], bv[nf], acc[mf][nf]);
  }

  short* cbase = cond + (((size_t)(blockIdx.y*64 + blockIdx.x)*8 + w)*16)*256 + lane*4;
  #pragma unroll
  for (int mf = 0; mf < 4; ++mf){
    f4 bb = *(const f4*)(cond_b + ch0 + orow + mf*16 + 4*g);
    #pragma unroll
    for (int nf = 0; nf < 4; ++nf){
      s4v pk;
      #pragma unroll
      for (int j = 0; j < 4; ++j) pk[j] = f2b(acc[mf][nf][j] + bb[j]);
      *(s4v*)(cbase + (mf*4 + nf)*256) = pk;
    }
  }
}

// ---------------- fused WaveNet layer ----------------
// grid (64 t-tiles, 4 batch), 512 threads (8 waves). 1 block/CU (128 KB LDS).
// flags: bit0 = first layer (write yacc), bit1 = last layer (skip res/h path)
__global__ __launch_bounds__(512, 2) void wn_layer(
    const short* __restrict__ hSrc, short* __restrict__ hDst,
    const short* __restrict__ W1l, const short* __restrict__ W2l,
    const short* __restrict__ Esl, const short* __restrict__ condl,
    const float* __restrict__ cb_l, const float* __restrict__ rsb_l,
    const float* __restrict__ ebl_l, float* __restrict__ yacc,
    int dil, int flags){

  __shared__ short Ht[3*64*NCH];   // 96 KB: 3 tap windows [64 t][256 c], XOR-swizzled
  __shared__ short xb[64*NCH];     // 32 KB: sigma exchange, then acts[t][c]

  const int tid  = threadIdx.x;
  const int w    = tid >> 6, lane = tid & 63;
  const int l15  = lane & 15, g = lane >> 4;
  const int tile = blockIdx.x, b = blockIdx.y;
  const int orow = w << 6;
  const int sw8  = (l15 & 7) << 3;   // B-read swizzle
  const bool first = flags & 1, last = flags & 2;

  f4 acc[4][4];
  #pragma unroll
  for (int mf = 0; mf < 4; ++mf)
    #pragma unroll
    for (int nf = 0; nf < 4; ++nf) acc[mf][nf] = (f4){0.f,0.f,0.f,0.f};

  bh8 Ap[2][4], Bp[2][4];

#define LA1(S, BUF) do{ const int _tap=(S)>>3, _kk=(S)&7; \
    const short* _p = W1l + (_tap<<17) + (w<<14) + (_kk<<11) + lane*8; \
    Ap[BUF][0]=*(const bh8*)(_p);      Ap[BUF][1]=*(const bh8*)(_p+512); \
    Ap[BUF][2]=*(const bh8*)(_p+1024); Ap[BUF][3]=*(const bh8*)(_p+1536); }while(0)
#define LB1(S, BUF) do{ const int _tap=(S)>>3, _kk=(S)&7; const int _c=(_kk*32+g*8)^sw8; \
    Bp[BUF][0]=*(const bh8*)(Ht + _tap*16384 + ( 0+l15)*NCH + _c); \
    Bp[BUF][1]=*(const bh8*)(Ht + _tap*16384 + (16+l15)*NCH + _c); \
    Bp[BUF][2]=*(const bh8*)(Ht + _tap*16384 + (32+l15)*NCH + _c); \
    Bp[BUF][3]=*(const bh8*)(Ht + _tap*16384 + (48+l15)*NCH + _c); }while(0)
#define LA2(S, BUF) do{ const int _kk=(S); \
    const short* _p = W2l + (w<<14) + (_kk<<11) + lane*8; \
    Ap[BUF][0]=*(const bh8*)(_p);      Ap[BUF][1]=*(const bh8*)(_p+512); \
    Ap[BUF][2]=*(const bh8*)(_p+1024); Ap[BUF][3]=*(const bh8*)(_p+1536); }while(0)
#define LB2(S, BUF) do{ const int _c=((S)*32+g*8)^sw8; \
    Bp[BUF][0]=*(const bh8*)(xb + ( 0+l15)*NCH + _c); \
    Bp[BUF][1]=*(const bh8*)(xb + (16+l15)*NCH + _c); \
    Bp[BUF][2]=*(const bh8*)(xb + (32+l15)*NCH + _c); \
    Bp[BUF][3]=*(const bh8*)(xb + (48+l15)*NCH + _c); }while(0)

  LA1(0, 0);   // issue first weight fragments before staging

  // ---- stage 3 h windows: global linear read -> swizzled LDS write ----
  {
    const int rsub = tid >> 5;            // 0..15
    const int innr = (tid & 31) << 3;     // short offset in row, 16B chunks
    #pragma unroll
    for (int tap = 0; tap < 3; ++tap){
      const int gbase = b*HROWS + PAD + tile*64 + (tap-1)*dil;
      #pragma unroll
      for (int ch = 0; ch < 4; ++ch){
        int r = ch*16 + rsub;
        u4 v = *(const u4*)(hSrc + (size_t)(gbase + r)*NCH + innr);
        *(u4*)(Ht + tap*16384 + r*NCH + (innr ^ ((r & 7) << 3))) = v;
      }
    }
  }
  __syncthreads();

  // ---- phase 1: dilated conv as 24 pipelined K-steps ----
  LB1(0, 0);
  #pragma unroll
  for (int s = 0; s < 24; ++s){
    const int cur = s & 1, nxt = cur ^ 1;
    if (s < 23){ LA1(s+1, nxt); LB1(s+1, nxt); }
    #pragma unroll
    for (int mf = 0; mf < 4; ++mf)
      #pragma unroll
      for (int nf = 0; nf < 4; ++nf)
        acc[mf][nf] = MFMA(Ap[cur][mf], Bp[cur][nf], acc[mf][nf]);
  }

  // ---- hoisted gate operands (coalesced; independent of LDS) ----
  s4v cvf[4][4];
  {
    const short* cbase = condl + (((size_t)tile*8 + w)*16)*256 + lane*4;
    #pragma unroll
    for (int mf = 0; mf < 4; ++mf)
      #pragma unroll
      for (int nf = 0; nf < 4; ++nf)
        cvf[mf][nf] = *(const s4v*)(cbase + (mf*4 + nf)*256);
  }
  float bias[4][4];
  #pragma unroll
  for (int mf = 0; mf < 4; ++mf){
    f4 t = *(const f4*)(cb_l + b*4096 + orow + mf*16 + 4*g);
    #pragma unroll
    for (int j = 0; j < 4; ++j) bias[mf][j] = t[j];
  }
  float rbv[4][4];
  #pragma unroll
  for (int mf = 0; mf < 4; ++mf){
    f4 t = *(const f4*)(rsb_l + orow + mf*16 + 4*g);
    #pragma unroll
    for (int j = 0; j < 4; ++j) rbv[mf][j] = t[j];
  }

  // ---- gate: waves 4-7 write sigma(in_act_hi); waves 0-3 tanh*sigma in place ----
  if (w >= 4){
    #pragma unroll
    for (int mf = 0; mf < 4; ++mf){
      #pragma unroll
      for (int nf = 0; nf < 4; ++nf){
        int tl = nf*16 + l15;
        s4v pk;
        #pragma unroll
        for (int j = 0; j < 4; ++j){
          float x = acc[mf][nf][j] + bias[mf][j] + b2f(cvf[mf][nf][j]);
          x = fminf(fmaxf(x, -30.f), 30.f);
          pk[j] = f2b(1.f/(1.f + __expf(-x)));
        }
        int cb0 = (orow - NCH) + mf*16 + 4*g;
        *(s4v*)(xb + tl*NCH + (cb0 ^ sw8)) = pk;
      }
    }
  }
  __syncthreads();
  if (w < 4){
    #pragma unroll
    for (int mf = 0; mf < 4; ++mf){
      #pragma unroll
      for (int nf = 0; nf < 4; ++nf){
        int tl = nf*16 + l15;
        int cb0 = orow + mf*16 + 4*g;
        short* p = xb + tl*NCH + (cb0 ^ sw8);
        s4v sg = *(const s4v*)p;
        s4v pk;
        #pragma unroll
        for (int j = 0; j < 4; ++j){
          float x = acc[mf][nf][j] + bias[mf][j] + b2f(cvf[mf][nf][j]);
          x = fminf(fmaxf(x, -30.f), 30.f);
          float e = __expf(2.f*x);
          float th = (e - 1.f)/(e + 1.f);
          pk[j] = f2b(th * b2f(sg[j]));
        }
        *(s4v*)p = pk;
      }
    }
    if (!last) LA2(0, 0);     // prefetch phase-2 res weights across the barrier
  }
  __syncthreads();

  // ---- phase 2 ----
  if (w < 4){
    if (!last){
      // res 1x1 GEMM (M=256), 8 pipelined K-steps; h += res
      #pragma unroll
      for (int mf = 0; mf < 4; ++mf)
        #pragma unroll
        for (int nf = 0; nf < 4; ++nf) acc[mf][nf] = (f4){0.f,0.f,0.f,0.f};
      LB2(0, 0);
      #pragma unroll
      for (int s = 0; s < 8; ++s){
        const int cur = s & 1, nxt = cur ^ 1;
        if (s < 7){ LA2(s+1, nxt); LB2(s+1, nxt); }
        #pragma unroll
        for (int mf = 0; mf < 4; ++mf)
          #pragma unroll
          for (int nf = 0; nf < 4; ++nf)
            acc[mf][nf] = MFMA(Ap[cur][mf], Bp[cur][nf], acc[mf][nf]);
      }
      #pragma unroll
      for (int mf = 0; mf < 4; ++mf){
        #pragma unroll
        for (int nf = 0; nf < 4; ++nf){
          int tl = nf*16 + l15;
          int cb0 = orow + mf*16 + 4*g;
          s4v hold = *(const s4v*)(Ht + 16384 + tl*NCH + (cb0 ^ sw8));  // center tap = h_old
          s4v pk;
          #pragma unroll
          for (int j = 0; j < 4; ++j)
            pk[j] = f2b(b2f(hold[j]) + acc[mf][nf][j] + rbv[mf][j]);
          *(s4v*)(hDst + ((size_t)b*HROWS + PAD + tile*64 + tl)*NCH + cb0) = pk;
        }
      }
    }
  } else {
    // skip path folded through end_w: y-partial (16 ch) for nf = w-4
    const int q = w - 4;
    f4 ya = (f4){0.f,0.f,0.f,0.f};
    #pragma unroll
    for (int kk = 0; kk < 8; ++kk){
      bh8 av = *(const bh8*)(Esl + ((size_t)kk*64 + lane)*8);
      int _c = (kk*32 + g*8) ^ sw8;
      bh8 bv = *(const bh8*)(xb + (q*16 + l15)*NCH + _c);
      ya = MFMA(av, bv, ya);
    }
    float* yp = yacc + ((size_t)b*T_LEN + tile*64 + q*16 + l15)*16 + g*4;
    f4 prev = first ? (f4){0.f,0.f,0.f,0.f} : *(const f4*)yp;
    f4 o;
    #pragma unroll
    for (int j = 0; j < 4; ++j) o[j] = prev[j] + ya[j] + ebl_l[g*4 + j];
    *(f4*)yp = o;
  }
#undef LA1
#undef LB1
#undef LA2
#undef LB2
}

// ---------------- final: y output from fp32 yacc (transpose [b][t][16] -> [b*16 split][t]) ----------------
__global__ void final_y(const float* __restrict__ yacc, float* __restrict__ y){
  __shared__ float tl[16][65];
  int b = blockIdx.y, t0 = blockIdx.x*64;
  int i = threadIdx.x;
  #pragma unroll
  for (int s = 0; s < 4; ++s){
    int idx = i + s*256;          // 0..1023
    int t = idx >> 4, o = idx & 15;
    tl[o][t] = yacc[((size_t)b*T_LEN + t0 + t)*16 + o];
  }
  __syncthreads();
  #pragma unroll
  for (int s = 0; s < 4; ++s){
    int idx = i + s*256;
    int o = idx >> 6, t = idx & 63;
    float v = tl[o][t];
    float* dst = (o < 8) ? (y + ((size_t)(b*8 + o))*T_LEN)
                         : (y + 131072 + ((size_t)(b*8 + o - 8))*T_LEN);
    dst[t0 + t] = v;
  }
}

extern "C" void kernel_launch(void* const* d_in, const int* in_sizes, int n_in,
                              void* d_out, int out_size, void* d_ws, size_t ws_size,
                              hipStream_t stream){
  const float* audio      = (const float*)d_in[0];
  const float* spect      = (const float*)d_in[1];
  const int*   pos        = (const int*)  d_in[2];
  const float* start_w    = (const float*)d_in[3];
  const float* start_b    = (const float*)d_in[4];
  const float* cond_w     = (const float*)d_in[5];
  const float* cond_b     = (const float*)d_in[6];
  const float* pos_emb_w  = (const float*)d_in[7];
  const float* pos_lin_w  = (const float*)d_in[8];
  const float* pos_lin_b  = (const float*)d_in[9];
  const float* in_w       = (const float*)d_in[10];
  const float* in_b       = (const float*)d_in[11];
  const float* rs_w       = (const float*)d_in[12];
  const float* rs_b       = (const float*)d_in[13];
  const float* rs_last_w  = (const float*)d_in[14];
  const float* rs_last_b  = (const float*)d_in[15];
  const float* end_w      = (const float*)d_in[16];
  const float* end_b      = (const float*)d_in[17];
  float* y = (float*)d_out;

  char* ws = (char*)d_ws;
  size_t off = 0;
  auto alloc = [&](size_t bytes) -> void* {
    void* p = ws + off;
    off += (bytes + 255) & ~(size_t)255;
    return p;
  };
  const size_t hBytes   = (size_t)BG*HROWS*NCH*2;     // 8,912,896
  const size_t condBy   = (size_t)4096*T_LEN*2;       // 33,554,432 (fragment-ordered)
  short* hA     = (short*)alloc(hBytes);
  short* hB     = (short*)alloc(hBytes);
  short* cond   = (short*)alloc(condBy);
  short* W1     = (short*)alloc((size_t)NL*3*M2*NCH*2);
  short* W2     = (short*)alloc((size_t)NL*4*16384*2);
  float* rsb8   = (float*)alloc((size_t)NL*M2*4);
  float* cb     = (float*)alloc((size_t)BG*4096*4);
  short* Wc     = (short*)alloc((size_t)4096*128*2);
  short* spectT = (short*)alloc((size_t)4096*128*2);
  short* Es     = (short*)alloc((size_t)NL*8*64*8*2);
  float* ebl    = (float*)alloc((size_t)NL*16*4);
  float* yacc   = (float*)alloc((size_t)BG*T_LEN*16*4);
  if (off > ws_size) return;  // insufficient workspace -> output stays zero (diagnosable)

  prep_w <<<4096, 256, 0, stream>>>(in_w, rs_w, rs_b, cond_w, W1, W2, rsb8, Wc);
  prep_pad<<<256, 256, 0, stream>>>(hA, hB);
  prep_E <<<NL, 256, 0, stream>>>(rs_w, rs_last_w, rs_b, rs_last_b, end_w, end_b, Es, ebl);
  prep_spectT<<<dim3(64, 2), 256, 0, stream>>>(spect, spectT);
  prep_cb<<<dim3(16, BG), 256, 0, stream>>>(pos, pos_emb_w, pos_lin_w, pos_lin_b, in_b, cb);
  prep_h0<<<dim3(64, BG), 256, 0, stream>>>(audio, start_w, start_b, hA);
  cond_gemm<<<dim3(64, 8), 512, 0, stream>>>(Wc, spectT, cond_b, cond);

  for (int l = 0; l < NL; ++l){
    const short* hS = (l & 1) ? hB : hA;
    short*       hD = (l & 1) ? hA : hB;
    int flags = (l == 0 ? 1 : 0) | (l == NL-1 ? 2 : 0);
    wn_layer<<<dim3(64, BG), 512, 0, stream>>>(
        hS, hD,
        W1 + (size_t)l*3*M2*NCH,
        W2 + (size_t)l*4*16384,
        Es + (size_t)l*8*64*8,
        cond + (size_t)l*64*8*16*256,
        cb + l*M2,
        rsb8 + l*M2,
        ebl + l*16,
        yacc, 1 << l, flags);
  }
  final_y<<<dim3(64, BG), 256, 0, stream>>>(yacc, y);
}

// Round 5
// 306.846 us; speedup vs baseline: 1.1287x; 1.1287x over previous
//
#include <hip/hip_runtime.h>
#include <stdint.h>

#define T_LEN 4096
#define PAD   128
#define HROWS (T_LEN + 2*PAD)   // 4352 rows (zero pad 128 each side)
#define NCH   256
#define M2    512
#define BG    4
#define NL    8

using f4  = __attribute__((ext_vector_type(4))) float;
using bh8 = __attribute__((ext_vector_type(8))) short;
using s4v = __attribute__((ext_vector_type(4))) short;
using u4  = __attribute__((ext_vector_type(4))) unsigned int;

static __device__ __forceinline__ short f2b(float f){
  unsigned u = __builtin_bit_cast(unsigned, f);
  unsigned r = (u + 0x7FFFu + ((u >> 16) & 1u)) >> 16;
  return (short)r;
}
static __device__ __forceinline__ float b2f(short s){
  unsigned u = ((unsigned)(unsigned short)s) << 16;
  return __builtin_bit_cast(float, u);
}

#define MFMA(a,b,c) __builtin_amdgcn_mfma_f32_16x16x32_bf16((a),(b),(c),0,0,0)

// ---------------- prep: weights -> bf16, fragment-ordered relayout ----------------
// W1s[l][tap][og(8)][kk(8)][mf(4)][lane(64)][8]: o = og*64+mf*16+(lane&15), c = kk*32+(lane>>4)*8+j
// W2s[l][og(4)][kk][mf][lane][8]: res half only (o<256); l==7 -> 0 (unused)
// rsb8[l][o]: l<7 -> rs_b[l][o]; l==7 unused (0)
// Wc[o][k] (k padded 80->128) = cond_w[o][k]
__global__ void prep_w(const float* __restrict__ in_w, const float* __restrict__ rs_w,
                       const float* __restrict__ rs_b, const float* __restrict__ cond_w,
                       short* __restrict__ W1, short* __restrict__ W2, float* __restrict__ rsb8,
                       short* __restrict__ Wc){
  const int n1 = NL*3*M2*NCH;           // 3,145,728
  const int n2 = NL*4*8*4*64*8;         // 524,288
  const int n3 = NL*M2;                 // 4,096
  const int n4 = 4096*128;              // 524,288
  for (int i = blockIdx.x*blockDim.x + threadIdx.x; i < n1+n2+n3+n4; i += gridDim.x*blockDim.x){
    if (i < n1){
      int j = i & 7, lane = (i >> 3) & 63, mf = (i >> 9) & 3, kk = (i >> 11) & 7, og = (i >> 14) & 7;
      int lt = i >> 17;                 // l*3 + tap
      int tap = lt % 3, l = lt / 3;
      int o = og*64 + mf*16 + (lane & 15);
      int c = kk*32 + (lane >> 4)*8 + j;
      W1[i] = f2b(in_w[(((l*M2 + o)*NCH + c)*3) + tap]);
    } else if (i < n1+n2){
      int q = i - n1;
      int j = q & 7, lane = (q >> 3) & 63, mf = (q >> 9) & 3, kk = (q >> 11) & 7, og = (q >> 14) & 3;
      int l = q >> 16;
      int o = og*64 + mf*16 + (lane & 15);    // 0..255 (res half)
      int c = kk*32 + (lane >> 4)*8 + j;
      W2[q] = (l < 7) ? f2b(rs_w[((size_t)(l*M2 + o))*NCH + c]) : (short)0;
    } else if (i < n1+n2+n3){
      int k = i - n1 - n2;
      int o = k & 511, l = k >> 9;
      rsb8[k] = (l < 7) ? rs_b[l*M2 + o] : 0.f;
    } else {
      int j = i - n1 - n2 - n3;
      int k = j & 127, o = j >> 7;
      Wc[j] = (k < 80) ? f2b(cond_w[o*80 + k]) : (short)0;
    }
  }
}

// ---------------- prep: zero only the pad rows of hA/hB ----------------
__global__ void prep_pad(short* __restrict__ hA, short* __restrict__ hB){
  int i = blockIdx.x*blockDim.x + threadIdx.x;     // 0..65535 (u4 writes)
  short* h = (i < 32768) ? hA : hB;
  int j = (i & 32767) << 3;                        // short index in pad region
  int b = j >> 16;                                 // 2*PAD*NCH = 65536 shorts per batch
  int r = j & 65535;
  int row = r >> 8;                                // 0..255
  int c = r & 255;
  int grow = (row < PAD) ? row : (T_LEN + PAD + (row - PAD));
  *(u4*)(h + ((size_t)b*HROWS + grow)*NCH + c) = (u4){0,0,0,0};
}

// ---------------- prep: E_l = end_w @ W2hi_l (16x256, fragment-ordered bf16) + ebl ----------------
// grid (NL, 16): one (layer, output-row) pair per block; 256 threads = c.
__global__ void prep_E(const float* __restrict__ rs_w, const float* __restrict__ rs_last_w,
                       const float* __restrict__ rs_b, const float* __restrict__ rs_last_b,
                       const float* __restrict__ end_w, const float* __restrict__ end_b,
                       short* __restrict__ Es, float* __restrict__ ebl){
  __shared__ float ew_s[256];
  __shared__ float red[256];
  const int l = blockIdx.x, o = blockIdx.y;
  const int c = threadIdx.x;
  ew_s[c] = end_w[o*256 + c];
  __syncthreads();
  const float* Wsrc = (l < 7) ? (rs_w + ((size_t)(l*M2 + NCH))*NCH) : rs_last_w;
  float acc = 0.f;
  #pragma unroll 8
  for (int cp = 0; cp < 256; ++cp)
    acc += ew_s[cp] * Wsrc[(size_t)cp*NCH + c];
  // Es[l][kk(8)][lane(64)][8]: o=lane&15, c=kk*32+(lane>>4)*8+j
  int kk = c >> 5, g = (c >> 3) & 3, j = c & 7;
  Es[(((size_t)l*8 + kk)*64 + g*16 + o)*8 + j] = f2b(acc);
  // ebl[l][o] = sum_cp ew[o][cp]*b_skip[cp] (+end_b at l==0)
  float bv = (l < 7) ? rs_b[l*M2 + NCH + c] : rs_last_b[c];
  red[c] = ew_s[c] * bv;
  __syncthreads();
  for (int s = 128; s > 0; s >>= 1){
    if (c < s) red[c] += red[c + s];
    __syncthreads();
  }
  if (c == 0) ebl[l*16 + o] = red[0] + ((l == 0) ? end_b[o] : 0.f);
}

// ---------------- prep: spectT[t][128 k] bf16 (padded transpose) ----------------
__global__ void prep_spectT(const float* __restrict__ spect, short* __restrict__ spectT){
  __shared__ float tile[64][65];
  int t0 = blockIdx.x*64, k0 = blockIdx.y*64;
  for (int i = threadIdx.x; i < 64*64; i += 256){
    int kr = i >> 6, tt = i & 63;
    int k = k0 + kr;
    tile[kr][tt] = (k < 80) ? spect[(size_t)k*T_LEN + t0 + tt] : 0.f;
  }
  __syncthreads();
  for (int i = threadIdx.x; i < 64*64; i += 256){
    int r = i >> 6, kk = i & 63;
    spectT[(size_t)(t0 + r)*128 + k0 + kk] = f2b(tile[kk][r]);
  }
}

// ---------------- prep: cb[b][ch] = in_b[ch] + pos_lin_b[ch] + pc[b][ch] ----------------
__global__ void prep_cb(const int* __restrict__ pos, const float* __restrict__ pos_emb_w,
                        const float* __restrict__ pos_lin_w, const float* __restrict__ pos_lin_b,
                        const float* __restrict__ in_b, float* __restrict__ cb){
  int b = blockIdx.y;
  int ch = blockIdx.x*blockDim.x + threadIdx.x;     // 0..4095
  int p = pos[b];
  float acc = pos_lin_b[ch] + in_b[ch];
  for (int k = 0; k < 128; ++k){
    float e = pos_emb_w[p*128 + k];
    e = e > 0.f ? e : 0.f;
    acc += e * pos_lin_w[ch*128 + k];
  }
  cb[b*4096 + ch] = acc;
}

// ---------------- prep: h0[b][t][c] (bf16, padded layout) ----------------
__global__ void prep_h0(const float* __restrict__ audio, const float* __restrict__ start_w,
                        const float* __restrict__ start_b, short* __restrict__ hA){
  __shared__ float sw[NCH*8];
  __shared__ float sb[NCH];
  int b = blockIdx.y, t0 = blockIdx.x*64;
  for (int i = threadIdx.x; i < NCH*8; i += 256) sw[i] = start_w[i];
  for (int i = threadIdx.x; i < NCH;   i += 256) sb[i] = start_b[i];
  __syncthreads();
  int t = t0 + (threadIdx.x & 63);
  int cg = threadIdx.x >> 6;
  float av[8];
  #pragma unroll
  for (int ic = 0; ic < 8; ++ic) av[ic] = audio[((size_t)(b*8 + ic))*T_LEN + t];
  short* dst = hA + ((size_t)b*HROWS + PAD + t)*NCH;
  for (int c = cg*64; c < cg*64 + 64; ++c){
    float acc = sb[c];
    #pragma unroll
    for (int ic = 0; ic < 8; ++ic) acc += sw[c*8 + ic]*av[ic];
    dst[c] = f2b(acc);
  }
}

// ---------------- cond GEMM: fragment-ordered output ----------------
// condF[l][tile(64)][w(8)][mfnf(16)][lane(64)][4]; grid (64 t-tiles, 8 layers)
__global__ __launch_bounds__(512, 2) void cond_gemm(
    const short* __restrict__ Wc, const short* __restrict__ spectT,
    const float* __restrict__ cond_b, short* __restrict__ cond){
  __shared__ short St[64*128];   // 16 KB, [t][k] XOR-swizzled
  const int tid = threadIdx.x;
  const int w = tid >> 6, lane = tid & 63;
  const int l15 = lane & 15, g = lane >> 4;
  const int t0 = blockIdx.x*64, ch0 = blockIdx.y*512;
  const int orow = w << 6;

  #pragma unroll
  for (int s = 0; s < 2; ++s){
    int id = tid + s*512;
    int r = id >> 4, c8 = (id & 15) << 3;
    u4 v = *(const u4*)(spectT + (size_t)(t0 + r)*128 + c8);
    *(u4*)(St + r*128 + (c8 ^ ((r & 7) << 3))) = v;
  }
  __syncthreads();

  f4 acc[4][4];
  #pragma unroll
  for (int mf = 0; mf < 4; ++mf)
    #pragma unroll
    for (int nf = 0; nf < 4; ++nf) acc[mf][nf] = (f4){0.f,0.f,0.f,0.f};

  #pragma unroll
  for (int kk = 0; kk < 3; ++kk){
    bh8 av[4], bv[4];
    #pragma unroll
    for (int mf = 0; mf < 4; ++mf)
      av[mf] = *(const bh8*)(Wc + (size_t)(ch0 + orow + mf*16 + l15)*128 + kk*32 + g*8);
    #pragma unroll
    for (int nf = 0; nf < 4; ++nf){
      int t = nf*16 + l15;
      bv[nf] = *(const bh8*)(St + t*128 + ((kk*32 + g*8) ^ ((t & 7) << 3)));
    }
    #pragma unroll
    for (int mf = 0; mf < 4; ++mf)
      #pragma unroll
      for (int nf = 0; nf < 4; ++nf)
        acc[mf][nf] = MFMA(av[mf], bv[nf], acc[mf][nf]);
  }

  short* cbase = cond + (((size_t)(blockIdx.y*64 + blockIdx.x)*8 + w)*16)*256 + lane*4;
  #pragma unroll
  for (int mf = 0; mf < 4; ++mf){
    f4 bb = *(const f4*)(cond_b + ch0 + orow + mf*16 + 4*g);
    #pragma unroll
    for (int nf = 0; nf < 4; ++nf){
      s4v pk;
      #pragma unroll
      for (int j = 0; j < 4; ++j) pk[j] = f2b(acc[mf][nf][j] + bb[j]);
      *(s4v*)(cbase + (mf*4 + nf)*256) = pk;
    }
  }
}

// ---------------- fused WaveNet layer ----------------
// grid (64 t-tiles, 4 batch), 512 threads (8 waves). 1 block/CU (128 KB LDS).
// flags: bit0 = first layer (write yacc), bit1 = last layer (skip res/h path)
__global__ __launch_bounds__(512, 2) void wn_layer(
    const short* __restrict__ hSrc, short* __restrict__ hDst,
    const short* __restrict__ W1l, const short* __restrict__ W2l,
    const short* __restrict__ Esl, const short* __restrict__ condl,
    const float* __restrict__ cb_l, const float* __restrict__ rsb_l,
    const float* __restrict__ ebl_l, float* __restrict__ yacc,
    int dil, int flags){

  __shared__ short Ht[3*64*NCH];   // 96 KB: 3 tap windows [64 t][256 c], XOR-swizzled
  __shared__ short xb[64*NCH];     // 32 KB: sigma exchange, then acts[t][c]

  const int tid  = threadIdx.x;
  const int w    = tid >> 6, lane = tid & 63;
  const int l15  = lane & 15, g = lane >> 4;
  const int tile = blockIdx.x, b = blockIdx.y;
  const int orow = w << 6;
  const int sw8  = (l15 & 7) << 3;   // B-read swizzle
  const bool first = flags & 1, last = flags & 2;

  f4 acc[4][4];
  #pragma unroll
  for (int mf = 0; mf < 4; ++mf)
    #pragma unroll
    for (int nf = 0; nf < 4; ++nf) acc[mf][nf] = (f4){0.f,0.f,0.f,0.f};

  bh8 Ap[2][4], Bp[2][4];

#define LA1(S, BUF) do{ const int _tap=(S)>>3, _kk=(S)&7; \
    const short* _p = W1l + (_tap<<17) + (w<<14) + (_kk<<11) + lane*8; \
    Ap[BUF][0]=*(const bh8*)(_p);      Ap[BUF][1]=*(const bh8*)(_p+512); \
    Ap[BUF][2]=*(const bh8*)(_p+1024); Ap[BUF][3]=*(const bh8*)(_p+1536); }while(0)
#define LB1(S, BUF) do{ const int _tap=(S)>>3, _kk=(S)&7; const int _c=(_kk*32+g*8)^sw8; \
    Bp[BUF][0]=*(const bh8*)(Ht + _tap*16384 + ( 0+l15)*NCH + _c); \
    Bp[BUF][1]=*(const bh8*)(Ht + _tap*16384 + (16+l15)*NCH + _c); \
    Bp[BUF][2]=*(const bh8*)(Ht + _tap*16384 + (32+l15)*NCH + _c); \
    Bp[BUF][3]=*(const bh8*)(Ht + _tap*16384 + (48+l15)*NCH + _c); }while(0)
#define LA2(S, BUF) do{ const int _kk=(S); \
    const short* _p = W2l + (w<<14) + (_kk<<11) + lane*8; \
    Ap[BUF][0]=*(const bh8*)(_p);      Ap[BUF][1]=*(const bh8*)(_p+512); \
    Ap[BUF][2]=*(const bh8*)(_p+1024); Ap[BUF][3]=*(const bh8*)(_p+1536); }while(0)
#define LB2(S, BUF) do{ const int _c=((S)*32+g*8)^sw8; \
    Bp[BUF][0]=*(const bh8*)(xb + ( 0+l15)*NCH + _c); \
    Bp[BUF][1]=*(const bh8*)(xb + (16+l15)*NCH + _c); \
    Bp[BUF][2]=*(const bh8*)(xb + (32+l15)*NCH + _c); \
    Bp[BUF][3]=*(const bh8*)(xb + (48+l15)*NCH + _c); }while(0)

  LA1(0, 0);   // issue first weight fragments before staging

  // ---- stage 3 h windows: global linear read -> swizzled LDS write ----
  {
    const int rsub = tid >> 5;            // 0..15
    const int innr = (tid & 31) << 3;     // short offset in row, 16B chunks
    #pragma unroll
    for (int tap = 0; tap < 3; ++tap){
      const int gbase = b*HROWS + PAD + tile*64 + (tap-1)*dil;
      #pragma unroll
      for (int ch = 0; ch < 4; ++ch){
        int r = ch*16 + rsub;
        u4 v = *(const u4*)(hSrc + (size_t)(gbase + r)*NCH + innr);
        *(u4*)(Ht + tap*16384 + r*NCH + (innr ^ ((r & 7) << 3))) = v;
      }
    }
  }
  __syncthreads();

  // ---- phase 1: dilated conv as 24 pipelined K-steps ----
  LB1(0, 0);
  #pragma unroll
  for (int s = 0; s < 24; ++s){
    const int cur = s & 1, nxt = cur ^ 1;
    if (s < 23){ LA1(s+1, nxt); LB1(s+1, nxt); }
    #pragma unroll
    for (int mf = 0; mf < 4; ++mf)
      #pragma unroll
      for (int nf = 0; nf < 4; ++nf)
        acc[mf][nf] = MFMA(Ap[cur][mf], Bp[cur][nf], acc[mf][nf]);
  }

  // ---- hoisted gate operands (coalesced; independent of LDS) ----
  s4v cvf[4][4];
  {
    const short* cbase = condl + (((size_t)tile*8 + w)*16)*256 + lane*4;
    #pragma unroll
    for (int mf = 0; mf < 4; ++mf)
      #pragma unroll
      for (int nf = 0; nf < 4; ++nf)
        cvf[mf][nf] = *(const s4v*)(cbase + (mf*4 + nf)*256);
  }
  float bias[4][4];
  #pragma unroll
  for (int mf = 0; mf < 4; ++mf){
    f4 t = *(const f4*)(cb_l + b*4096 + orow + mf*16 + 4*g);
    #pragma unroll
    for (int j = 0; j < 4; ++j) bias[mf][j] = t[j];
  }
  float rbv[4][4];
  #pragma unroll
  for (int mf = 0; mf < 4; ++mf){
    f4 t = *(const f4*)(rsb_l + orow + mf*16 + 4*g);
    #pragma unroll
    for (int j = 0; j < 4; ++j) rbv[mf][j] = t[j];
  }

  // ---- gate: waves 4-7 write sigma(in_act_hi); waves 0-3 tanh*sigma in place ----
  if (w >= 4){
    #pragma unroll
    for (int mf = 0; mf < 4; ++mf){
      #pragma unroll
      for (int nf = 0; nf < 4; ++nf){
        int tl = nf*16 + l15;
        s4v pk;
        #pragma unroll
        for (int j = 0; j < 4; ++j){
          float x = acc[mf][nf][j] + bias[mf][j] + b2f(cvf[mf][nf][j]);
          x = fminf(fmaxf(x, -30.f), 30.f);
          pk[j] = f2b(1.f/(1.f + __expf(-x)));
        }
        int cb0 = (orow - NCH) + mf*16 + 4*g;
        *(s4v*)(xb + tl*NCH + (cb0 ^ sw8)) = pk;
      }
    }
  }
  __syncthreads();
  if (w < 4){
    #pragma unroll
    for (int mf = 0; mf < 4; ++mf){
      #pragma unroll
      for (int nf = 0; nf < 4; ++nf){
        int tl = nf*16 + l15;
        int cb0 = orow + mf*16 + 4*g;
        short* p = xb + tl*NCH + (cb0 ^ sw8);
        s4v sg = *(const s4v*)p;
        s4v pk;
        #pragma unroll
        for (int j = 0; j < 4; ++j){
          float x = acc[mf][nf][j] + bias[mf][j] + b2f(cvf[mf][nf][j]);
          x = fminf(fmaxf(x, -30.f), 30.f);
          float e = __expf(2.f*x);
          float th = (e - 1.f)/(e + 1.f);
          pk[j] = f2b(th * b2f(sg[j]));
        }
        *(s4v*)p = pk;
      }
    }
    if (!last) LA2(0, 0);     // prefetch phase-2 res weights across the barrier
  }
  __syncthreads();

  // ---- phase 2 ----
  if (w < 4){
    if (!last){
      // res 1x1 GEMM (M=256), 8 pipelined K-steps; h += res
      #pragma unroll
      for (int mf = 0; mf < 4; ++mf)
        #pragma unroll
        for (int nf = 0; nf < 4; ++nf) acc[mf][nf] = (f4){0.f,0.f,0.f,0.f};
      LB2(0, 0);
      #pragma unroll
      for (int s = 0; s < 8; ++s){
        const int cur = s & 1, nxt = cur ^ 1;
        if (s < 7){ LA2(s+1, nxt); LB2(s+1, nxt); }
        #pragma unroll
        for (int mf = 0; mf < 4; ++mf)
          #pragma unroll
          for (int nf = 0; nf < 4; ++nf)
            acc[mf][nf] = MFMA(Ap[cur][mf], Bp[cur][nf], acc[mf][nf]);
      }
      #pragma unroll
      for (int mf = 0; mf < 4; ++mf){
        #pragma unroll
        for (int nf = 0; nf < 4; ++nf){
          int tl = nf*16 + l15;
          int cb0 = orow + mf*16 + 4*g;
          s4v hold = *(const s4v*)(Ht + 16384 + tl*NCH + (cb0 ^ sw8));  // center tap = h_old
          s4v pk;
          #pragma unroll
          for (int j = 0; j < 4; ++j)
            pk[j] = f2b(b2f(hold[j]) + acc[mf][nf][j] + rbv[mf][j]);
          *(s4v*)(hDst + ((size_t)b*HROWS + PAD + tile*64 + tl)*NCH + cb0) = pk;
        }
      }
    }
  } else {
    // skip path folded through end_w: y-partial (16 ch) for nf = w-4
    const int q = w - 4;
    f4 ya = (f4){0.f,0.f,0.f,0.f};
    #pragma unroll
    for (int kk = 0; kk < 8; ++kk){
      bh8 av = *(const bh8*)(Esl + ((size_t)kk*64 + lane)*8);
      int _c = (kk*32 + g*8) ^ sw8;
      bh8 bv = *(const bh8*)(xb + (q*16 + l15)*NCH + _c);
      ya = MFMA(av, bv, ya);
    }
    float* yp = yacc + ((size_t)b*T_LEN + tile*64 + q*16 + l15)*16 + g*4;
    f4 prev = first ? (f4){0.f,0.f,0.f,0.f} : *(const f4*)yp;
    f4 o;
    #pragma unroll
    for (int j = 0; j < 4; ++j) o[j] = prev[j] + ya[j] + ebl_l[g*4 + j];
    *(f4*)yp = o;
  }
#undef LA1
#undef LB1
#undef LA2
#undef LB2
}

// ---------------- final: y output from fp32 yacc (transpose [b][t][16] -> [b*16 split][t]) ----------------
__global__ void final_y(const float* __restrict__ yacc, float* __restrict__ y){
  __shared__ float tl[16][65];
  int b = blockIdx.y, t0 = blockIdx.x*64;
  int i = threadIdx.x;
  #pragma unroll
  for (int s = 0; s < 4; ++s){
    int idx = i + s*256;          // 0..1023
    int t = idx >> 4, o = idx & 15;
    tl[o][t] = yacc[((size_t)b*T_LEN + t0 + t)*16 + o];
  }
  __syncthreads();
  #pragma unroll
  for (int s = 0; s < 4; ++s){
    int idx = i + s*256;
    int o = idx >> 6, t = idx & 63;
    float v = tl[o][t];
    float* dst = (o < 8) ? (y + ((size_t)(b*8 + o))*T_LEN)
                         : (y + 131072 + ((size_t)(b*8 + o - 8))*T_LEN);
    dst[t0 + t] = v;
  }
}

extern "C" void kernel_launch(void* const* d_in, const int* in_sizes, int n_in,
                              void* d_out, int out_size, void* d_ws, size_t ws_size,
                              hipStream_t stream){
  const float* audio      = (const float*)d_in[0];
  const float* spect      = (const float*)d_in[1];
  const int*   pos        = (const int*)  d_in[2];
  const float* start_w    = (const float*)d_in[3];
  const float* start_b    = (const float*)d_in[4];
  const float* cond_w     = (const float*)d_in[5];
  const float* cond_b     = (const float*)d_in[6];
  const float* pos_emb_w  = (const float*)d_in[7];
  const float* pos_lin_w  = (const float*)d_in[8];
  const float* pos_lin_b  = (const float*)d_in[9];
  const float* in_w       = (const float*)d_in[10];
  const float* in_b       = (const float*)d_in[11];
  const float* rs_w       = (const float*)d_in[12];
  const float* rs_b       = (const float*)d_in[13];
  const float* rs_last_w  = (const float*)d_in[14];
  const float* rs_last_b  = (const float*)d_in[15];
  const float* end_w      = (const float*)d_in[16];
  const float* end_b      = (const float*)d_in[17];
  float* y = (float*)d_out;

  char* ws = (char*)d_ws;
  size_t off = 0;
  auto alloc = [&](size_t bytes) -> void* {
    void* p = ws + off;
    off += (bytes + 255) & ~(size_t)255;
    return p;
  };
  const size_t hBytes   = (size_t)BG*HROWS*NCH*2;     // 8,912,896
  const size_t condBy   = (size_t)4096*T_LEN*2;       // 33,554,432 (fragment-ordered)
  short* hA     = (short*)alloc(hBytes);
  short* hB     = (short*)alloc(hBytes);
  short* cond   = (short*)alloc(condBy);
  short* W1     = (short*)alloc((size_t)NL*3*M2*NCH*2);
  short* W2     = (short*)alloc((size_t)NL*4*16384*2);
  float* rsb8   = (float*)alloc((size_t)NL*M2*4);
  float* cb     = (float*)alloc((size_t)BG*4096*4);
  short* Wc     = (short*)alloc((size_t)4096*128*2);
  short* spectT = (short*)alloc((size_t)4096*128*2);
  short* Es     = (short*)alloc((size_t)NL*8*64*8*2);
  float* ebl    = (float*)alloc((size_t)NL*16*4);
  float* yacc   = (float*)alloc((size_t)BG*T_LEN*16*4);
  if (off > ws_size) return;  // insufficient workspace -> output stays zero (diagnosable)

  prep_w <<<4096, 256, 0, stream>>>(in_w, rs_w, rs_b, cond_w, W1, W2, rsb8, Wc);
  prep_pad<<<256, 256, 0, stream>>>(hA, hB);
  prep_E <<<dim3(NL, 16), 256, 0, stream>>>(rs_w, rs_last_w, rs_b, rs_last_b, end_w, end_b, Es, ebl);
  prep_spectT<<<dim3(64, 2), 256, 0, stream>>>(spect, spectT);
  prep_cb<<<dim3(16, BG), 256, 0, stream>>>(pos, pos_emb_w, pos_lin_w, pos_lin_b, in_b, cb);
  prep_h0<<<dim3(64, BG), 256, 0, stream>>>(audio, start_w, start_b, hA);
  cond_gemm<<<dim3(64, 8), 512, 0, stream>>>(Wc, spectT, cond_b, cond);

  for (int l = 0; l < NL; ++l){
    const short* hS = (l & 1) ? hB : hA;
    short*       hD = (l & 1) ? hA : hB;
    int flags = (l == 0 ? 1 : 0) | (l == NL-1 ? 2 : 0);
    wn_layer<<<dim3(64, BG), 512, 0, stream>>>(
        hS, hD,
        W1 + (size_t)l*3*M2*NCH,
        W2 + (size_t)l*4*16384,
        Es + (size_t)l*8*64*8,
        cond + (size_t)l*64*8*16*256,
        cb + l*M2,
        rsb8 + l*M2,
        ebl + l*16,
        yacc, 1 << l, flags);
  }
  final_y<<<dim3(64, BG), 256, 0, stream>>>(yacc, y);
}

// Round 6
// 273.096 us; speedup vs baseline: 1.2682x; 1.1236x over previous
//
#include <hip/hip_runtime.h>
#include <stdint.h>

#define T_LEN 4096
#define PAD   128
#define HROWS (T_LEN + 2*PAD)   // 4352 rows (zero pad 128 each side)
#define NCH   256
#define M2    512
#define BG    4
#define NL    8

using f4  = __attribute__((ext_vector_type(4))) float;
using bh8 = __attribute__((ext_vector_type(8))) short;
using s4v = __attribute__((ext_vector_type(4))) short;
using u4  = __attribute__((ext_vector_type(4))) unsigned int;

static __device__ __forceinline__ short f2b(float f){
  unsigned u = __builtin_bit_cast(unsigned, f);
  unsigned r = (u + 0x7FFFu + ((u >> 16) & 1u)) >> 16;
  return (short)r;
}
static __device__ __forceinline__ float b2f(short s){
  unsigned u = ((unsigned)(unsigned short)s) << 16;
  return __builtin_bit_cast(float, u);
}

#define MFMA(a,b,c) __builtin_amdgcn_mfma_f32_16x16x32_bf16((a),(b),(c),0,0,0)

// ================= fused prep: all weight/input preprocessing in ONE launch =================
// block ranges: [0,1024) prep_w | [1024,1280) pad | [1280,1408) prep_E
//               [1408,1536) spectT | [1536,1600) cb | [1600,1856) h0
#define W_BLK0   0
#define PAD_BLK0 1024
#define E_BLK0   1280
#define ST_BLK0  1408
#define CB_BLK0  1536
#define H0_BLK0  1600
#define ALL_BLKS 1856

__global__ __launch_bounds__(256) void prep_all(
    const float* __restrict__ audio, const float* __restrict__ spect,
    const int* __restrict__ pos, const float* __restrict__ start_w,
    const float* __restrict__ start_b, const float* __restrict__ cond_w,
    const float* __restrict__ pos_emb_w, const float* __restrict__ pos_lin_w,
    const float* __restrict__ pos_lin_b, const float* __restrict__ in_w,
    const float* __restrict__ in_b, const float* __restrict__ rs_w,
    const float* __restrict__ rs_b, const float* __restrict__ rs_last_w,
    const float* __restrict__ rs_last_b, const float* __restrict__ end_w,
    const float* __restrict__ end_b,
    short* __restrict__ W1, short* __restrict__ W2, float* __restrict__ rsb8,
    short* __restrict__ Wc, short* __restrict__ hA, short* __restrict__ hB,
    short* __restrict__ Es, float* __restrict__ ebl, short* __restrict__ spectT,
    float* __restrict__ cb){
  __shared__ float smem[4224];   // 16.5 KB, shared by variants
  const int bid = blockIdx.x, tid = threadIdx.x;

  if (bid < PAD_BLK0){
    // ---- weights -> bf16 fragment-ordered ----
    const int n1 = NL*3*M2*NCH, n2 = NL*4*8*4*64*8, n3 = NL*M2, n4 = 4096*128;
    for (int i = bid*256 + tid; i < n1+n2+n3+n4; i += 1024*256){
      if (i < n1){
        int j = i & 7, lane = (i >> 3) & 63, mf = (i >> 9) & 3, kk = (i >> 11) & 7, og = (i >> 14) & 7;
        int lt = i >> 17;
        int tap = lt % 3, l = lt / 3;
        int o = og*64 + mf*16 + (lane & 15);
        int c = kk*32 + (lane >> 4)*8 + j;
        W1[i] = f2b(in_w[(((l*M2 + o)*NCH + c)*3) + tap]);
      } else if (i < n1+n2){
        int q = i - n1;
        int j = q & 7, lane = (q >> 3) & 63, mf = (q >> 9) & 3, kk = (q >> 11) & 7, og = (q >> 14) & 3;
        int l = q >> 16;
        int o = og*64 + mf*16 + (lane & 15);
        int c = kk*32 + (lane >> 4)*8 + j;
        W2[q] = (l < 7) ? f2b(rs_w[((size_t)(l*M2 + o))*NCH + c]) : (short)0;
      } else if (i < n1+n2+n3){
        int k = i - n1 - n2;
        int o = k & 511, l = k >> 9;
        rsb8[k] = (l < 7) ? rs_b[l*M2 + o] : 0.f;
      } else {
        int j = i - n1 - n2 - n3;
        int k = j & 127, o = j >> 7;
        Wc[j] = (k < 80) ? f2b(cond_w[o*80 + k]) : (short)0;
      }
    }
  } else if (bid < E_BLK0){
    // ---- zero pad rows of hA/hB ----
    int i = (bid - PAD_BLK0)*256 + tid;              // 0..65535
    short* h = (i < 32768) ? hA : hB;
    int j = (i & 32767) << 3;
    int b = j >> 16;
    int r = j & 65535;
    int row = r >> 8, c = r & 255;
    int grow = (row < PAD) ? row : (T_LEN + PAD + (row - PAD));
    *(u4*)(h + ((size_t)b*HROWS + grow)*NCH + c) = (u4){0,0,0,0};
  } else if (bid < ST_BLK0){
    // ---- E_l = end_w @ W2hi_l + ebl ----
    float* ew_s = smem; float* red = smem + 256;
    int e = bid - E_BLK0;
    const int l = e >> 4, o = e & 15;
    const int c = tid;
    ew_s[c] = end_w[o*256 + c];
    __syncthreads();
    const float* Wsrc = (l < 7) ? (rs_w + ((size_t)(l*M2 + NCH))*NCH) : rs_last_w;
    float acc = 0.f;
    #pragma unroll 8
    for (int cp = 0; cp < 256; ++cp)
      acc += ew_s[cp] * Wsrc[(size_t)cp*NCH + c];
    int kk = c >> 5, g = (c >> 3) & 3, j = c & 7;
    Es[(((size_t)l*8 + kk)*64 + g*16 + o)*8 + j] = f2b(acc);
    float bv = (l < 7) ? rs_b[l*M2 + NCH + c] : rs_last_b[c];
    red[c] = ew_s[c] * bv;
    __syncthreads();
    for (int s = 128; s > 0; s >>= 1){
      if (c < s) red[c] += red[c + s];
      __syncthreads();
    }
    if (c == 0) ebl[l*16 + o] = red[0] + ((l == 0) ? end_b[o] : 0.f);
  } else if (bid < CB_BLK0){
    // ---- spectT transpose (padded 80->128) ----
    float (*tile)[65] = (float(*)[65])smem;
    int e = bid - ST_BLK0;
    int t0 = (e & 63)*64, k0 = (e >> 6)*64;
    for (int i = tid; i < 64*64; i += 256){
      int kr = i >> 6, tt = i & 63;
      int k = k0 + kr;
      tile[kr][tt] = (k < 80) ? spect[(size_t)k*T_LEN + t0 + tt] : 0.f;
    }
    __syncthreads();
    for (int i = tid; i < 64*64; i += 256){
      int r = i >> 6, kk = i & 63;
      spectT[(size_t)(t0 + r)*128 + k0 + kk] = f2b(tile[kk][r]);
    }
  } else if (bid < H0_BLK0){
    // ---- cb[b][ch] = in_b + pos_lin_b + pc ----
    int e = bid - CB_BLK0;
    int b = e >> 4;
    int ch = (e & 15)*256 + tid;
    int p = pos[b];
    float acc = pos_lin_b[ch] + in_b[ch];
    for (int k = 0; k < 128; ++k){
      float ev = pos_emb_w[p*128 + k];
      ev = ev > 0.f ? ev : 0.f;
      acc += ev * pos_lin_w[ch*128 + k];
    }
    cb[b*4096 + ch] = acc;
  } else {
    // ---- h0 ----
    float* sw = smem; float* sb = smem + 2048;
    int e = bid - H0_BLK0;
    int b = e >> 6, t0 = (e & 63)*64;
    for (int i = tid; i < NCH*8; i += 256) sw[i] = start_w[i];
    for (int i = tid; i < NCH;   i += 256) sb[i] = start_b[i];
    __syncthreads();
    int t = t0 + (tid & 63);
    int cg = tid >> 6;
    float av[8];
    #pragma unroll
    for (int ic = 0; ic < 8; ++ic) av[ic] = audio[((size_t)(b*8 + ic))*T_LEN + t];
    short* dst = hA + ((size_t)b*HROWS + PAD + t)*NCH;
    for (int c = cg*64; c < cg*64 + 64; ++c){
      float acc = sb[c];
      #pragma unroll
      for (int ic = 0; ic < 8; ++ic) acc += sw[c*8 + ic]*av[ic];
      dst[c] = f2b(acc);
    }
  }
}

// ---------------- cond GEMM: fragment-ordered output ----------------
// condF[l][tile(64)][w(8)][mfnf(16)][lane(64)][4]; grid (64 t-tiles, 8 layers)
__global__ __launch_bounds__(512, 2) void cond_gemm(
    const short* __restrict__ Wc, const short* __restrict__ spectT,
    const float* __restrict__ cond_b, short* __restrict__ cond){
  __shared__ short St[64*128];   // 16 KB, [t][k] XOR-swizzled
  const int tid = threadIdx.x;
  const int w = tid >> 6, lane = tid & 63;
  const int l15 = lane & 15, g = lane >> 4;
  const int t0 = blockIdx.x*64, ch0 = blockIdx.y*512;
  const int orow = w << 6;

  #pragma unroll
  for (int s = 0; s < 2; ++s){
    int id = tid + s*512;
    int r = id >> 4, c8 = (id & 15) << 3;
    u4 v = *(const u4*)(spectT + (size_t)(t0 + r)*128 + c8);
    *(u4*)(St + r*128 + (c8 ^ ((r & 7) << 3))) = v;
  }
  __syncthreads();

  f4 acc[4][4];
  #pragma unroll
  for (int mf = 0; mf < 4; ++mf)
    #pragma unroll
    for (int nf = 0; nf < 4; ++nf) acc[mf][nf] = (f4){0.f,0.f,0.f,0.f};

  #pragma unroll
  for (int kk = 0; kk < 3; ++kk){
    bh8 av[4], bv[4];
    #pragma unroll
    for (int mf = 0; mf < 4; ++mf)
      av[mf] = *(const bh8*)(Wc + (size_t)(ch0 + orow + mf*16 + l15)*128 + kk*32 + g*8);
    #pragma unroll
    for (int nf = 0; nf < 4; ++nf){
      int t = nf*16 + l15;
      bv[nf] = *(const bh8*)(St + t*128 + ((kk*32 + g*8) ^ ((t & 7) << 3)));
    }
    #pragma unroll
    for (int mf = 0; mf < 4; ++mf)
      #pragma unroll
      for (int nf = 0; nf < 4; ++nf)
        acc[mf][nf] = MFMA(av[mf], bv[nf], acc[mf][nf]);
  }

  short* cbase = cond + (((size_t)(blockIdx.y*64 + blockIdx.x)*8 + w)*16)*256 + lane*4;
  #pragma unroll
  for (int mf = 0; mf < 4; ++mf){
    f4 bb = *(const f4*)(cond_b + ch0 + orow + mf*16 + 4*g);
    #pragma unroll
    for (int nf = 0; nf < 4; ++nf){
      s4v pk;
      #pragma unroll
      for (int j = 0; j < 4; ++j) pk[j] = f2b(acc[mf][nf][j] + bb[j]);
      *(s4v*)(cbase + (mf*4 + nf)*256) = pk;
    }
  }
}

// ---------------- fused WaveNet layer ----------------
// grid (64 t-tiles, 4 batch), 512 threads (8 waves). 1 block/CU (128 KB LDS).
// flags: bit0 = first layer (write yacc), bit1 = last layer (skip res/h path)
__global__ __launch_bounds__(512, 2) void wn_layer(
    const short* __restrict__ hSrc, short* __restrict__ hDst,
    const short* __restrict__ W1l, const short* __restrict__ W2l,
    const short* __restrict__ Esl, const short* __restrict__ condl,
    const float* __restrict__ cb_l, const float* __restrict__ rsb_l,
    const float* __restrict__ ebl_l, float* __restrict__ yacc,
    int dil, int flags){

  __shared__ short Ht[3*64*NCH];   // 96 KB: 3 tap windows [64 t][256 c], XOR-swizzled
  __shared__ short xb[64*NCH];     // 32 KB: sigma exchange, then acts[t][c]

  const int tid  = threadIdx.x;
  const int w    = tid >> 6, lane = tid & 63;
  const int l15  = lane & 15, g = lane >> 4;
  const int tile = blockIdx.x, b = blockIdx.y;
  const int orow = w << 6;
  const int sw8  = (l15 & 7) << 3;   // B-read swizzle
  const bool first = flags & 1, last = flags & 2;

  f4 acc[4][4];
  #pragma unroll
  for (int mf = 0; mf < 4; ++mf)
    #pragma unroll
    for (int nf = 0; nf < 4; ++nf) acc[mf][nf] = (f4){0.f,0.f,0.f,0.f};

  bh8 Ap[3][4], Bp[3][4];

#define LA1(S, BUF) do{ const int _tap=(S)>>3, _kk=(S)&7; \
    const short* _p = W1l + (_tap<<17) + (w<<14) + (_kk<<11) + lane*8; \
    Ap[BUF][0]=*(const bh8*)(_p);      Ap[BUF][1]=*(const bh8*)(_p+512); \
    Ap[BUF][2]=*(const bh8*)(_p+1024); Ap[BUF][3]=*(const bh8*)(_p+1536); }while(0)
#define LB1(S, BUF) do{ const int _tap=(S)>>3, _kk=(S)&7; const int _c=(_kk*32+g*8)^sw8; \
    Bp[BUF][0]=*(const bh8*)(Ht + _tap*16384 + ( 0+l15)*NCH + _c); \
    Bp[BUF][1]=*(const bh8*)(Ht + _tap*16384 + (16+l15)*NCH + _c); \
    Bp[BUF][2]=*(const bh8*)(Ht + _tap*16384 + (32+l15)*NCH + _c); \
    Bp[BUF][3]=*(const bh8*)(Ht + _tap*16384 + (48+l15)*NCH + _c); }while(0)
#define LA2(S, BUF) do{ const int _kk=(S); \
    const short* _p = W2l + (w<<14) + (_kk<<11) + lane*8; \
    Ap[BUF][0]=*(const bh8*)(_p);      Ap[BUF][1]=*(const bh8*)(_p+512); \
    Ap[BUF][2]=*(const bh8*)(_p+1024); Ap[BUF][3]=*(const bh8*)(_p+1536); }while(0)
#define LB2(S, BUF) do{ const int _c=((S)*32+g*8)^sw8; \
    Bp[BUF][0]=*(const bh8*)(xb + ( 0+l15)*NCH + _c); \
    Bp[BUF][1]=*(const bh8*)(xb + (16+l15)*NCH + _c); \
    Bp[BUF][2]=*(const bh8*)(xb + (32+l15)*NCH + _c); \
    Bp[BUF][3]=*(const bh8*)(xb + (48+l15)*NCH + _c); }while(0)

  LA1(0, 0);   // issue first weight fragments before staging

  // ---- stage 3 h windows: global linear read -> swizzled LDS write ----
  {
    const int rsub = tid >> 5;            // 0..15
    const int innr = (tid & 31) << 3;     // short offset in row, 16B chunks
    #pragma unroll
    for (int tap = 0; tap < 3; ++tap){
      const int gbase = b*HROWS + PAD + tile*64 + (tap-1)*dil;
      #pragma unroll
      for (int ch = 0; ch < 4; ++ch){
        int r = ch*16 + rsub;
        u4 v = *(const u4*)(hSrc + (size_t)(gbase + r)*NCH + innr);
        *(u4*)(Ht + tap*16384 + r*NCH + (innr ^ ((r & 7) << 3))) = v;
      }
    }
  }
  // hoisted cond fragment loads: independent of LDS, HBM latency hides under phase 1
  s4v cvf[4][4];
  {
    const short* cbase = condl + (((size_t)tile*8 + w)*16)*256 + lane*4;
    #pragma unroll
    for (int mf = 0; mf < 4; ++mf)
      #pragma unroll
      for (int nf = 0; nf < 4; ++nf)
        cvf[mf][nf] = *(const s4v*)(cbase + (mf*4 + nf)*256);
  }
  __syncthreads();

  // ---- phase 1: dilated conv, depth-2 pipelined (3-buffer rotation) ----
  LB1(0, 0);
  LA1(1, 1); LB1(1, 1);
  #pragma unroll
  for (int s = 0; s < 24; ++s){
    const int cur = s % 3, pf = (s+2) % 3;
    if (s < 22){ LA1(s+2, pf); LB1(s+2, pf); }
    #pragma unroll
    for (int mf = 0; mf < 4; ++mf)
      #pragma unroll
      for (int nf = 0; nf < 4; ++nf)
        acc[mf][nf] = MFMA(Ap[cur][mf], Bp[cur][nf], acc[mf][nf]);
  }

  float bias[4][4];
  #pragma unroll
  for (int mf = 0; mf < 4; ++mf){
    f4 t = *(const f4*)(cb_l + b*4096 + orow + mf*16 + 4*g);
    #pragma unroll
    for (int j = 0; j < 4; ++j) bias[mf][j] = t[j];
  }
  float rbv[4][4];
  #pragma unroll
  for (int mf = 0; mf < 4; ++mf){
    f4 t = *(const f4*)(rsb_l + orow + mf*16 + 4*g);
    #pragma unroll
    for (int j = 0; j < 4; ++j) rbv[mf][j] = t[j];
  }

  // ---- gate: waves 4-7 write sigma(in_act_hi); waves 0-3 tanh*sigma in place ----
  if (w >= 4){
    #pragma unroll
    for (int mf = 0; mf < 4; ++mf){
      #pragma unroll
      for (int nf = 0; nf < 4; ++nf){
        int tl = nf*16 + l15;
        s4v pk;
        #pragma unroll
        for (int j = 0; j < 4; ++j){
          float x = acc[mf][nf][j] + bias[mf][j] + b2f(cvf[mf][nf][j]);
          x = fminf(fmaxf(x, -30.f), 30.f);
          pk[j] = f2b(1.f/(1.f + __expf(-x)));
        }
        int cb0 = (orow - NCH) + mf*16 + 4*g;
        *(s4v*)(xb + tl*NCH + (cb0 ^ sw8)) = pk;
      }
    }
  }
  __syncthreads();
  if (w < 4){
    #pragma unroll
    for (int mf = 0; mf < 4; ++mf){
      #pragma unroll
      for (int nf = 0; nf < 4; ++nf){
        int tl = nf*16 + l15;
        int cb0 = orow + mf*16 + 4*g;
        short* p = xb + tl*NCH + (cb0 ^ sw8);
        s4v sg = *(const s4v*)p;
        s4v pk;
        #pragma unroll
        for (int j = 0; j < 4; ++j){
          float x = acc[mf][nf][j] + bias[mf][j] + b2f(cvf[mf][nf][j]);
          x = fminf(fmaxf(x, -30.f), 30.f);
          float e = __expf(2.f*x);
          float th = (e - 1.f)/(e + 1.f);
          pk[j] = f2b(th * b2f(sg[j]));
        }
        *(s4v*)p = pk;
      }
    }
    if (!last) LA2(0, 0);     // prefetch phase-2 res weights across the barrier
  }
  __syncthreads();

  // ---- phase 2 ----
  if (w < 4){
    if (!last){
      // res 1x1 GEMM (M=256), 8 pipelined K-steps; h += res
      #pragma unroll
      for (int mf = 0; mf < 4; ++mf)
        #pragma unroll
        for (int nf = 0; nf < 4; ++nf) acc[mf][nf] = (f4){0.f,0.f,0.f,0.f};
      LB2(0, 0);
      #pragma unroll
      for (int s = 0; s < 8; ++s){
        const int cur = s & 1, nxt = cur ^ 1;
        if (s < 7){ LA2(s+1, nxt); LB2(s+1, nxt); }
        #pragma unroll
        for (int mf = 0; mf < 4; ++mf)
          #pragma unroll
          for (int nf = 0; nf < 4; ++nf)
            acc[mf][nf] = MFMA(Ap[cur][mf], Bp[cur][nf], acc[mf][nf]);
      }
      #pragma unroll
      for (int mf = 0; mf < 4; ++mf){
        #pragma unroll
        for (int nf = 0; nf < 4; ++nf){
          int tl = nf*16 + l15;
          int cb0 = orow + mf*16 + 4*g;
          s4v hold = *(const s4v*)(Ht + 16384 + tl*NCH + (cb0 ^ sw8));  // center tap = h_old
          s4v pk;
          #pragma unroll
          for (int j = 0; j < 4; ++j)
            pk[j] = f2b(b2f(hold[j]) + acc[mf][nf][j] + rbv[mf][j]);
          *(s4v*)(hDst + ((size_t)b*HROWS + PAD + tile*64 + tl)*NCH + cb0) = pk;
        }
      }
    }
  } else {
    // skip path folded through end_w: y-partial (16 ch) for nf = w-4
    const int q = w - 4;
    f4 ya = (f4){0.f,0.f,0.f,0.f};
    #pragma unroll
    for (int kk = 0; kk < 8; ++kk){
      bh8 av = *(const bh8*)(Esl + ((size_t)kk*64 + lane)*8);
      int _c = (kk*32 + g*8) ^ sw8;
      bh8 bv = *(const bh8*)(xb + (q*16 + l15)*NCH + _c);
      ya = MFMA(av, bv, ya);
    }
    float* yp = yacc + ((size_t)b*T_LEN + tile*64 + q*16 + l15)*16 + g*4;
    f4 prev = first ? (f4){0.f,0.f,0.f,0.f} : *(const f4*)yp;
    f4 o;
    #pragma unroll
    for (int j = 0; j < 4; ++j) o[j] = prev[j] + ya[j] + ebl_l[g*4 + j];
    *(f4*)yp = o;
  }
#undef LA1
#undef LB1
#undef LA2
#undef LB2
}

// ---------------- final: y output from fp32 yacc (transpose [b][t][16] -> [b*16 split][t]) ----------------
__global__ void final_y(const float* __restrict__ yacc, float* __restrict__ y){
  __shared__ float tl[16][65];
  int b = blockIdx.y, t0 = blockIdx.x*64;
  int i = threadIdx.x;
  #pragma unroll
  for (int s = 0; s < 4; ++s){
    int idx = i + s*256;          // 0..1023
    int t = idx >> 4, o = idx & 15;
    tl[o][t] = yacc[((size_t)b*T_LEN + t0 + t)*16 + o];
  }
  __syncthreads();
  #pragma unroll
  for (int s = 0; s < 4; ++s){
    int idx = i + s*256;
    int o = idx >> 6, t = idx & 63;
    float v = tl[o][t];
    float* dst = (o < 8) ? (y + ((size_t)(b*8 + o))*T_LEN)
                         : (y + 131072 + ((size_t)(b*8 + o - 8))*T_LEN);
    dst[t0 + t] = v;
  }
}

extern "C" void kernel_launch(void* const* d_in, const int* in_sizes, int n_in,
                              void* d_out, int out_size, void* d_ws, size_t ws_size,
                              hipStream_t stream){
  const float* audio      = (const float*)d_in[0];
  const float* spect      = (const float*)d_in[1];
  const int*   pos        = (const int*)  d_in[2];
  const float* start_w    = (const float*)d_in[3];
  const float* start_b    = (const float*)d_in[4];
  const float* cond_w     = (const float*)d_in[5];
  const float* cond_b     = (const float*)d_in[6];
  const float* pos_emb_w  = (const float*)d_in[7];
  const float* pos_lin_w  = (const float*)d_in[8];
  const float* pos_lin_b  = (const float*)d_in[9];
  const float* in_w       = (const float*)d_in[10];
  const float* in_b       = (const float*)d_in[11];
  const float* rs_w       = (const float*)d_in[12];
  const float* rs_b       = (const float*)d_in[13];
  const float* rs_last_w  = (const float*)d_in[14];
  const float* rs_last_b  = (const float*)d_in[15];
  const float* end_w      = (const float*)d_in[16];
  const float* end_b      = (const float*)d_in[17];
  float* y = (float*)d_out;

  char* ws = (char*)d_ws;
  size_t off = 0;
  auto alloc = [&](size_t bytes) -> void* {
    void* p = ws + off;
    off += (bytes + 255) & ~(size_t)255;
    return p;
  };
  const size_t hBytes   = (size_t)BG*HROWS*NCH*2;     // 8,912,896
  const size_t condBy   = (size_t)4096*T_LEN*2;       // 33,554,432 (fragment-ordered)
  short* hA     = (short*)alloc(hBytes);
  short* hB     = (short*)alloc(hBytes);
  short* cond   = (short*)alloc(condBy);
  short* W1     = (short*)alloc((size_t)NL*3*M2*NCH*2);
  short* W2     = (short*)alloc((size_t)NL*4*16384*2);
  float* rsb8   = (float*)alloc((size_t)NL*M2*4);
  float* cb     = (float*)alloc((size_t)BG*4096*4);
  short* Wc     = (short*)alloc((size_t)4096*128*2);
  short* spectT = (short*)alloc((size_t)4096*128*2);
  short* Es     = (short*)alloc((size_t)NL*8*64*8*2);
  float* ebl    = (float*)alloc((size_t)NL*16*4);
  float* yacc   = (float*)alloc((size_t)BG*T_LEN*16*4);
  if (off > ws_size) return;  // insufficient workspace -> output stays zero (diagnosable)

  prep_all<<<ALL_BLKS, 256, 0, stream>>>(
      audio, spect, pos, start_w, start_b, cond_w, pos_emb_w, pos_lin_w,
      pos_lin_b, in_w, in_b, rs_w, rs_b, rs_last_w, rs_last_b, end_w, end_b,
      W1, W2, rsb8, Wc, hA, hB, Es, ebl, spectT, cb);

  cond_gemm<<<dim3(64, 8), 512, 0, stream>>>(Wc, spectT, cond_b, cond);

  for (int l = 0; l < NL; ++l){
    const short* hS = (l & 1) ? hB : hA;
    short*       hD = (l & 1) ? hA : hB;
    int flags = (l == 0 ? 1 : 0) | (l == NL-1 ? 2 : 0);
    wn_layer<<<dim3(64, BG), 512, 0, stream>>>(
        hS, hD,
        W1 + (size_t)l*3*M2*NCH,
        W2 + (size_t)l*4*16384,
        Es + (size_t)l*8*64*8,
        cond + (size_t)l*64*8*16*256,
        cb + l*M2,
        rsb8 + l*M2,
        ebl + l*16,
        yacc, 1 << l, flags);
  }
  final_y<<<dim3(64, BG), 256, 0, stream>>>(yacc, y);
}

// Round 7
// 219.609 us; speedup vs baseline: 1.5770x; 1.2436x over previous
//
#include <hip/hip_runtime.h>
#include <stdint.h>

#define T_LEN 4096
#define PAD   128
#define HROWS (T_LEN + 2*PAD)   // 4352 rows (zero pad 128 each side)
#define NCH   256
#define M2    512
#define BG    4
#define NL    8

using f4  = __attribute__((ext_vector_type(4))) float;
using bh8 = __attribute__((ext_vector_type(8))) short;
using s4v = __attribute__((ext_vector_type(4))) short;
using u4  = __attribute__((ext_vector_type(4))) unsigned int;

static __device__ __forceinline__ short f2b(float f){
  unsigned u = __builtin_bit_cast(unsigned, f);
  unsigned r = (u + 0x7FFFu + ((u >> 16) & 1u)) >> 16;
  return (short)r;
}
static __device__ __forceinline__ float b2f(short s){
  unsigned u = ((unsigned)(unsigned short)s) << 16;
  return __builtin_bit_cast(float, u);
}

#define MFMA(a,b,c) __builtin_amdgcn_mfma_f32_16x16x32_bf16((a),(b),(c),0,0,0)

// Per-wave row ownership: wave w owns rows {w*32 + f*16} (f=0,1; tanh half)
// and {256 + w*32 + (f-2)*16} (f=2,3; sigma half).
// W1n[l][tap][w(8)][kk(8)][f(4)][lane(64)][8]
// Wcn[l][w(8)][kk(4; K pad 80->128)][f(4)][lane][8]
// W2n[l][w(8)][kk(8)][f(2; res rows w*32+f*16)][lane][8]
// Es[l][kk(8)][lane][8] (M=16)  -- unchanged

// ================= fused prep: all preprocessing in ONE launch =================
// block ranges: [0,1024) weights | [1024,1280) pad | [1280,1408) prep_E
//               [1408,1536) spectT | [1536,1600) cb | [1600,1856) h0
#define PAD_BLK0 1024
#define E_BLK0   1280
#define ST_BLK0  1408
#define CB_BLK0  1536
#define H0_BLK0  1600
#define ALL_BLKS 1856

__global__ __launch_bounds__(256) void prep_all(
    const float* __restrict__ audio, const float* __restrict__ spect,
    const int* __restrict__ pos, const float* __restrict__ start_w,
    const float* __restrict__ start_b, const float* __restrict__ cond_w,
    const float* __restrict__ cond_b, const float* __restrict__ pos_emb_w,
    const float* __restrict__ pos_lin_w, const float* __restrict__ pos_lin_b,
    const float* __restrict__ in_w, const float* __restrict__ in_b,
    const float* __restrict__ rs_w, const float* __restrict__ rs_b,
    const float* __restrict__ rs_last_w, const float* __restrict__ rs_last_b,
    const float* __restrict__ end_w, const float* __restrict__ end_b,
    short* __restrict__ W1, short* __restrict__ W2, short* __restrict__ Wcn,
    float* __restrict__ rsb8, short* __restrict__ hA, short* __restrict__ hB,
    short* __restrict__ Es, float* __restrict__ ebl, short* __restrict__ spectT,
    float* __restrict__ cb){
  __shared__ float smem[4224];   // 16.5 KB, shared by variants
  const int bid = blockIdx.x, tid = threadIdx.x;

  if (bid < PAD_BLK0){
    // ---- weights -> bf16 fragment-ordered (new per-wave split layout) ----
    const int n1 = NL*3*8*8*4*512;   // 3,145,728 W1n
    const int n2 = NL*8*8*2*512;     // 524,288   W2n
    const int n4 = NL*8*4*4*512;     // 524,288   Wcn
    const int n3 = NL*M2;            // 4,096     rsb8
    for (int i = bid*256 + tid; i < n1+n2+n4+n3; i += 1024*256){
      if (i < n1){
        int j = i & 7, lane = (i >> 3) & 63, f = (i >> 9) & 3, kk = (i >> 11) & 7, w = (i >> 14) & 7;
        int lt = i >> 17;               // l*3 + tap
        int tap = lt % 3, l = lt / 3;
        int o = (f < 2) ? (w*32 + f*16 + (lane & 15)) : (256 + w*32 + (f-2)*16 + (lane & 15));
        int c = kk*32 + (lane >> 4)*8 + j;
        W1[i] = f2b(in_w[(((l*M2 + o)*NCH + c)*3) + tap]);
      } else if (i < n1+n2){
        int q = i - n1;
        int j = q & 7, lane = (q >> 3) & 63, f = (q >> 9) & 1, kk = (q >> 10) & 7, w = (q >> 13) & 7;
        int l = q >> 16;
        int o = w*32 + f*16 + (lane & 15);          // res rows 0..255
        int c = kk*32 + (lane >> 4)*8 + j;
        W2[q] = (l < 7) ? f2b(rs_w[((size_t)(l*M2 + o))*NCH + c]) : (short)0;
      } else if (i < n1+n2+n4){
        int r = i - n1 - n2;
        int j = r & 7, lane = (r >> 3) & 63, f = (r >> 9) & 3, kk = (r >> 11) & 3, w = (r >> 13) & 7;
        int l = r >> 16;
        int o = (f < 2) ? (w*32 + f*16 + (lane & 15)) : (256 + w*32 + (f-2)*16 + (lane & 15));
        int k = kk*32 + (lane >> 4)*8 + j;
        Wcn[r] = (k < 80) ? f2b(cond_w[(size_t)(l*M2 + o)*80 + k]) : (short)0;
      } else {
        int k = i - n1 - n2 - n4;
        int o = k & 511, l = k >> 9;
        rsb8[k] = (l < 7) ? rs_b[l*M2 + o] : 0.f;
      }
    }
  } else if (bid < E_BLK0){
    // ---- zero pad rows of hA/hB ----
    int i = (bid - PAD_BLK0)*256 + tid;              // 0..65535
    short* h = (i < 32768) ? hA : hB;
    int j = (i & 32767) << 3;
    int b = j >> 16;
    int r = j & 65535;
    int row = r >> 8, c = r & 255;
    int grow = (row < PAD) ? row : (T_LEN + PAD + (row - PAD));
    *(u4*)(h + ((size_t)b*HROWS + grow)*NCH + c) = (u4){0,0,0,0};
  } else if (bid < ST_BLK0){
    // ---- E_l = end_w @ W2hi_l + ebl ----
    float* ew_s = smem; float* red = smem + 256;
    int e = bid - E_BLK0;
    const int l = e >> 4, o = e & 15;
    const int c = tid;
    ew_s[c] = end_w[o*256 + c];
    __syncthreads();
    const float* Wsrc = (l < 7) ? (rs_w + ((size_t)(l*M2 + NCH))*NCH) : rs_last_w;
    float acc = 0.f;
    #pragma unroll 8
    for (int cp = 0; cp < 256; ++cp)
      acc += ew_s[cp] * Wsrc[(size_t)cp*NCH + c];
    int kk = c >> 5, g = (c >> 3) & 3, j = c & 7;
    Es[(((size_t)l*8 + kk)*64 + g*16 + o)*8 + j] = f2b(acc);
    float bv = (l < 7) ? rs_b[l*M2 + NCH + c] : rs_last_b[c];
    red[c] = ew_s[c] * bv;
    __syncthreads();
    for (int s = 128; s > 0; s >>= 1){
      if (c < s) red[c] += red[c + s];
      __syncthreads();
    }
    if (c == 0) ebl[l*16 + o] = red[0] + ((l == 0) ? end_b[o] : 0.f);
  } else if (bid < CB_BLK0){
    // ---- spectT transpose (padded 80->128) ----
    float (*tile)[65] = (float(*)[65])smem;
    int e = bid - ST_BLK0;
    int t0 = (e & 63)*64, k0 = (e >> 6)*64;
    for (int i = tid; i < 64*64; i += 256){
      int kr = i >> 6, tt = i & 63;
      int k = k0 + kr;
      tile[kr][tt] = (k < 80) ? spect[(size_t)k*T_LEN + t0 + tt] : 0.f;
    }
    __syncthreads();
    for (int i = tid; i < 64*64; i += 256){
      int r = i >> 6, kk = i & 63;
      spectT[(size_t)(t0 + r)*128 + k0 + kk] = f2b(tile[kk][r]);
    }
  } else if (bid < H0_BLK0){
    // ---- cb[b][ch] = in_b + pos_lin_b + cond_b + pc ----
    int e = bid - CB_BLK0;
    int b = e >> 4;
    int ch = (e & 15)*256 + tid;
    int p = pos[b];
    float acc = pos_lin_b[ch] + in_b[ch] + cond_b[ch];
    for (int k = 0; k < 128; ++k){
      float ev = pos_emb_w[p*128 + k];
      ev = ev > 0.f ? ev : 0.f;
      acc += ev * pos_lin_w[ch*128 + k];
    }
    cb[b*4096 + ch] = acc;
  } else {
    // ---- h0 ----
    float* sw = smem; float* sb = smem + 2048;
    int e = bid - H0_BLK0;
    int b = e >> 6, t0 = (e & 63)*64;
    for (int i = tid; i < NCH*8; i += 256) sw[i] = start_w[i];
    for (int i = tid; i < NCH;   i += 256) sb[i] = start_b[i];
    __syncthreads();
    int t = t0 + (tid & 63);
    int cg = tid >> 6;
    float av[8];
    #pragma unroll
    for (int ic = 0; ic < 8; ++ic) av[ic] = audio[((size_t)(b*8 + ic))*T_LEN + t];
    short* dst = hA + ((size_t)b*HROWS + PAD + t)*NCH;
    for (int c = cg*64; c < cg*64 + 64; ++c){
      float acc = sb[c];
      #pragma unroll
      for (int ic = 0; ic < 8; ++ic) acc += sw[c*8 + ic]*av[ic];
      dst[c] = f2b(acc);
    }
  }
}

// ---------------- fused WaveNet layer (cond GEMM fused, in-register gate) ----------------
// grid (64 t-tiles, 4 batch), 512 threads (8 waves). 1 block/CU (144 KB LDS).
// flags: bit0 = first layer (init yacc), bit1 = last layer (skip res/h path)
__global__ __launch_bounds__(512, 2) void wn_layer(
    const short* __restrict__ hSrc, short* __restrict__ hDst,
    const short* __restrict__ W1l, const short* __restrict__ W2l,
    const short* __restrict__ Wcl, const short* __restrict__ Esl,
    const short* __restrict__ spectTp,
    const float* __restrict__ cb_l, const float* __restrict__ rsb_l,
    const float* __restrict__ ebl_l, float* __restrict__ yacc,
    int dil, int flags){

  __shared__ short Ht[3*64*NCH];   // 96 KB: 3 tap windows [64 t][256 c], XOR-swizzled
  __shared__ short xb[64*NCH];     // 32 KB: acts[t][c]
  __shared__ short St[64*128];     // 16 KB: spectT tile [t][k], XOR-swizzled

  const int tid  = threadIdx.x;
  const int w    = tid >> 6, lane = tid & 63;
  const int l15  = lane & 15, g = lane >> 4;
  const int tile = blockIdx.x, b = blockIdx.y;
  const int sw8  = (l15 & 7) << 3;   // B-read swizzle (row&7 == l15&7)
  const bool first = flags & 1, last = flags & 2;

  f4 acc[4][4];
  #pragma unroll
  for (int f = 0; f < 4; ++f)
    #pragma unroll
    for (int nf = 0; nf < 4; ++nf) acc[f][nf] = (f4){0.f,0.f,0.f,0.f};

  bh8 Ap[3][4], Bp[3][4];

  // steps 0..2: cond (A=Wcn, B=St, K=96); steps 3..26: conv (A=W1n, B=Ht)
#define LAc(S, BUF) do{ const short* _p = Wcl + w*8192 + (S)*2048 + lane*8; \
    Ap[BUF][0]=*(const bh8*)(_p);      Ap[BUF][1]=*(const bh8*)(_p+512); \
    Ap[BUF][2]=*(const bh8*)(_p+1024); Ap[BUF][3]=*(const bh8*)(_p+1536); }while(0)
#define LBc(S, BUF) do{ const int _c=((S)*32+g*8)^sw8; \
    Bp[BUF][0]=*(const bh8*)(St + ( 0+l15)*128 + _c); \
    Bp[BUF][1]=*(const bh8*)(St + (16+l15)*128 + _c); \
    Bp[BUF][2]=*(const bh8*)(St + (32+l15)*128 + _c); \
    Bp[BUF][3]=*(const bh8*)(St + (48+l15)*128 + _c); }while(0)
#define LA1(S, BUF) do{ const int _tap=(S)>>3, _kk=(S)&7; \
    const short* _p = W1l + _tap*131072 + w*16384 + _kk*2048 + lane*8; \
    Ap[BUF][0]=*(const bh8*)(_p);      Ap[BUF][1]=*(const bh8*)(_p+512); \
    Ap[BUF][2]=*(const bh8*)(_p+1024); Ap[BUF][3]=*(const bh8*)(_p+1536); }while(0)
#define LB1(S, BUF) do{ const int _tap=(S)>>3, _kk=(S)&7; const int _c=(_kk*32+g*8)^sw8; \
    Bp[BUF][0]=*(const bh8*)(Ht + _tap*16384 + ( 0+l15)*NCH + _c); \
    Bp[BUF][1]=*(const bh8*)(Ht + _tap*16384 + (16+l15)*NCH + _c); \
    Bp[BUF][2]=*(const bh8*)(Ht + _tap*16384 + (32+l15)*NCH + _c); \
    Bp[BUF][3]=*(const bh8*)(Ht + _tap*16384 + (48+l15)*NCH + _c); }while(0)
#define LAX(S, BUF) do{ if((S)<3) LAc((S),BUF); else LA1((S)-3,BUF); }while(0)
#define LBX(S, BUF) do{ if((S)<3) LBc((S),BUF); else LB1((S)-3,BUF); }while(0)
#define LA2(S, BUF) do{ \
    const short* _p = W2l + w*8192 + (S)*1024 + lane*8; \
    Ap[BUF][0]=*(const bh8*)(_p);      Ap[BUF][1]=*(const bh8*)(_p+512); }while(0)
#define LB2(S, BUF) do{ const int _c=((S)*32+g*8)^sw8; \
    Bp[BUF][0]=*(const bh8*)(xb + ( 0+l15)*NCH + _c); \
    Bp[BUF][1]=*(const bh8*)(xb + (16+l15)*NCH + _c); \
    Bp[BUF][2]=*(const bh8*)(xb + (32+l15)*NCH + _c); \
    Bp[BUF][3]=*(const bh8*)(xb + (48+l15)*NCH + _c); }while(0)

  LAX(0, 0);   // issue first (cond) weight fragments before staging

  // ---- stage: 3 h windows + spectT tile -> swizzled LDS ----
  {
    const int rsub = tid >> 5;            // 0..15
    const int innr = (tid & 31) << 3;     // short offset in row, 16B chunks
    #pragma unroll
    for (int tap = 0; tap < 3; ++tap){
      const int gbase = b*HROWS + PAD + tile*64 + (tap-1)*dil;
      #pragma unroll
      for (int ch = 0; ch < 4; ++ch){
        int r = ch*16 + rsub;
        u4 v = *(const u4*)(hSrc + (size_t)(gbase + r)*NCH + innr);
        *(u4*)(Ht + tap*16384 + r*NCH + (innr ^ ((r & 7) << 3))) = v;
      }
    }
    #pragma unroll
    for (int s = 0; s < 2; ++s){
      int id = tid + s*512;
      int r = id >> 4, c8 = (id & 15) << 3;
      u4 v = *(const u4*)(spectTp + (size_t)(tile*64 + r)*128 + c8);
      *(u4*)(St + r*128 + (c8 ^ ((r & 7) << 3))) = v;
    }
  }
  __syncthreads();

  // ---- phase 1: cond (3) + dilated conv (24) = 27 depth-2 pipelined K-steps ----
  LBX(0, 0);
  LAX(1, 1); LBX(1, 1);
  #pragma unroll
  for (int s = 0; s < 27; ++s){
    const int cur = s % 3, pf = (s+2) % 3;
    if (s < 25){ LAX(s+2, pf); LBX(s+2, pf); }
    #pragma unroll
    for (int f = 0; f < 4; ++f)
      #pragma unroll
      for (int nf = 0; nf < 4; ++nf)
        acc[f][nf] = MFMA(Ap[cur][f], Bp[cur][nf], acc[f][nf]);
  }

  float bias[4][4];
  #pragma unroll
  for (int f = 0; f < 4; ++f){
    int ch = ((f < 2) ? (w*32 + f*16) : (256 + w*32 + (f-2)*16)) + 4*g;
    f4 t = *(const f4*)(cb_l + b*4096 + ch);
    #pragma unroll
    for (int j = 0; j < 4; ++j) bias[f][j] = t[j];
  }
  float rbv[2][4];
  #pragma unroll
  for (int f = 0; f < 2; ++f){
    f4 t = *(const f4*)(rsb_l + w*32 + f*16 + 4*g);
    #pragma unroll
    for (int j = 0; j < 4; ++j) rbv[f][j] = t[j];
  }

  // ---- gate: fully in-register (wave owns both tanh and sigma halves) ----
  #pragma unroll
  for (int f = 0; f < 2; ++f){
    #pragma unroll
    for (int nf = 0; nf < 4; ++nf){
      int tl = nf*16 + l15;
      s4v pk;
      #pragma unroll
      for (int j = 0; j < 4; ++j){
        float xl = acc[f][nf][j]   + bias[f][j];
        float xh = acc[f+2][nf][j] + bias[f+2][j];
        xl = fminf(fmaxf(xl, -30.f), 30.f);
        xh = fminf(fmaxf(xh, -30.f), 30.f);
        float e2 = __expf(2.f*xl);
        float th = (e2 - 1.f)/(e2 + 1.f);
        float sg = 1.f/(1.f + __expf(-xh));
        pk[j] = f2b(th * sg);
      }
      *(s4v*)(xb + tl*NCH + ((w*32 + f*16 + 4*g) ^ sw8)) = pk;
    }
  }
  if (!last) LA2(0, 0);     // prefetch phase-2 res weights across the barrier
  __syncthreads();

  // ---- phase 2: res 1x1 (all 8 waves, 32 rows each) + skip-folded y partial ----
  if (!last){
    #pragma unroll
    for (int f = 0; f < 2; ++f)
      #pragma unroll
      for (int nf = 0; nf < 4; ++nf) acc[f][nf] = (f4){0.f,0.f,0.f,0.f};
    LB2(0, 0);
    #pragma unroll
    for (int s = 0; s < 8; ++s){
      const int cur = s & 1, nxt = cur ^ 1;
      if (s < 7){ LA2(s+1, nxt); LB2(s+1, nxt); }
      #pragma unroll
      for (int f = 0; f < 2; ++f)
        #pragma unroll
        for (int nf = 0; nf < 4; ++nf)
          acc[f][nf] = MFMA(Ap[cur][f], Bp[cur][nf], acc[f][nf]);
    }
    #pragma unroll
    for (int f = 0; f < 2; ++f){
      #pragma unroll
      for (int nf = 0; nf < 4; ++nf){
        int tl = nf*16 + l15;
        int cb0 = w*32 + f*16 + 4*g;
        s4v hold = *(const s4v*)(Ht + 16384 + tl*NCH + (cb0 ^ sw8));  // center tap = h_old
        s4v pk;
        #pragma unroll
        for (int j = 0; j < 4; ++j)
          pk[j] = f2b(b2f(hold[j]) + acc[f][nf][j] + rbv[f][j]);
        *(s4v*)(hDst + ((size_t)b*HROWS + PAD + tile*64 + tl)*NCH + cb0) = pk;
      }
    }
  }
  // skip path folded through end_w: wave w computes t-quarter (w&3), kk-half (w>>2)
  {
    const int nfq = w & 3, kh = w >> 2;
    f4 ya = (f4){0.f,0.f,0.f,0.f};
    #pragma unroll
    for (int s = 0; s < 4; ++s){
      int kks = kh*4 + s;
      bh8 av = *(const bh8*)(Esl + ((size_t)kks*64 + lane)*8);
      bh8 bv = *(const bh8*)(xb + (nfq*16 + l15)*NCH + ((kks*32 + g*8) ^ sw8));
      ya = MFMA(av, bv, ya);
    }
    float* yp = yacc + (((size_t)(b*T_LEN + tile*64 + nfq*16 + l15))*2 + kh)*16 + g*4;
    f4 prev = first ? (f4){0.f,0.f,0.f,0.f} : *(const f4*)yp;
    f4 o;
    #pragma unroll
    for (int j = 0; j < 4; ++j)
      o[j] = prev[j] + ya[j] + ((kh == 0) ? ebl_l[g*4 + j] : 0.f);
    *(f4*)yp = o;
  }
#undef LAc
#undef LBc
#undef LA1
#undef LB1
#undef LAX
#undef LBX
#undef LA2
#undef LB2
}

// ---------------- final: y from fp32 yacc2 slots (sum + transpose) ----------------
__global__ void final_y(const float* __restrict__ yacc, float* __restrict__ y){
  __shared__ float tl[16][65];
  int b = blockIdx.y, t0 = blockIdx.x*64;
  int i = threadIdx.x;
  #pragma unroll
  for (int s = 0; s < 4; ++s){
    int idx = i + s*256;          // 0..1023
    int t = idx >> 4, o = idx & 15;
    size_t base = ((size_t)(b*T_LEN + t0 + t))*32 + o;
    tl[o][t] = yacc[base] + yacc[base + 16];
  }
  __syncthreads();
  #pragma unroll
  for (int s = 0; s < 4; ++s){
    int idx = i + s*256;
    int o = idx >> 6, t = idx & 63;
    float v = tl[o][t];
    float* dst = (o < 8) ? (y + ((size_t)(b*8 + o))*T_LEN)
                         : (y + 131072 + ((size_t)(b*8 + o - 8))*T_LEN);
    dst[t0 + t] = v;
  }
}

extern "C" void kernel_launch(void* const* d_in, const int* in_sizes, int n_in,
                              void* d_out, int out_size, void* d_ws, size_t ws_size,
                              hipStream_t stream){
  const float* audio      = (const float*)d_in[0];
  const float* spect      = (const float*)d_in[1];
  const int*   pos        = (const int*)  d_in[2];
  const float* start_w    = (const float*)d_in[3];
  const float* start_b    = (const float*)d_in[4];
  const float* cond_w     = (const float*)d_in[5];
  const float* cond_b     = (const float*)d_in[6];
  const float* pos_emb_w  = (const float*)d_in[7];
  const float* pos_lin_w  = (const float*)d_in[8];
  const float* pos_lin_b  = (const float*)d_in[9];
  const float* in_w       = (const float*)d_in[10];
  const float* in_b       = (const float*)d_in[11];
  const float* rs_w       = (const float*)d_in[12];
  const float* rs_b       = (const float*)d_in[13];
  const float* rs_last_w  = (const float*)d_in[14];
  const float* rs_last_b  = (const float*)d_in[15];
  const float* end_w      = (const float*)d_in[16];
  const float* end_b      = (const float*)d_in[17];
  float* y = (float*)d_out;

  char* ws = (char*)d_ws;
  size_t off = 0;
  auto alloc = [&](size_t bytes) -> void* {
    void* p = ws + off;
    off += (bytes + 255) & ~(size_t)255;
    return p;
  };
  const size_t hBytes = (size_t)BG*HROWS*NCH*2;     // 8,912,896
  short* hA     = (short*)alloc(hBytes);
  short* hB     = (short*)alloc(hBytes);
  short* W1     = (short*)alloc((size_t)NL*3*8*8*4*512*2);   // 6 MB
  short* W2     = (short*)alloc((size_t)NL*8*8*2*512*2);     // 1 MB
  short* Wcn    = (short*)alloc((size_t)NL*8*4*4*512*2);     // 1 MB
  float* rsb8   = (float*)alloc((size_t)NL*M2*4);
  float* cb     = (float*)alloc((size_t)BG*4096*4);
  short* spectT = (short*)alloc((size_t)4096*128*2);
  short* Es     = (short*)alloc((size_t)NL*8*64*8*2);
  float* ebl    = (float*)alloc((size_t)NL*16*4);
  float* yacc   = (float*)alloc((size_t)BG*T_LEN*2*16*4);    // 2 MB (2 slots)
  if (off > ws_size) return;  // insufficient workspace -> output stays zero (diagnosable)

  prep_all<<<ALL_BLKS, 256, 0, stream>>>(
      audio, spect, pos, start_w, start_b, cond_w, cond_b, pos_emb_w, pos_lin_w,
      pos_lin_b, in_w, in_b, rs_w, rs_b, rs_last_w, rs_last_b, end_w, end_b,
      W1, W2, Wcn, rsb8, hA, hB, Es, ebl, spectT, cb);

  for (int l = 0; l < NL; ++l){
    const short* hS = (l & 1) ? hB : hA;
    short*       hD = (l & 1) ? hA : hB;
    int flags = (l == 0 ? 1 : 0) | (l == NL-1 ? 2 : 0);
    wn_layer<<<dim3(64, BG), 512, 0, stream>>>(
        hS, hD,
        W1 + (size_t)l*3*131072,
        W2 + (size_t)l*65536,
        Wcn + (size_t)l*65536,
        Es + (size_t)l*4096,
        spectT,
        cb + l*M2,
        rsb8 + l*M2,
        ebl + l*16,
        yacc, 1 << l, flags);
  }
  final_y<<<dim3(64, BG), 256, 0, stream>>>(yacc, y);
}